// Round 12
// baseline (7100.465 us; speedup 1.0000x reference)
//
#include <hip/hip_runtime.h>
#include <math.h>

#define NN_  10000
#define NE_  320000
#define IND  64
#define HID  128
#define G3   384   // 3*HID
#define HC1  512   // 4 heads * 128
#define OUTD 64

typedef _Float16 h2f __attribute__((ext_vector_type(2)));
union UI2H { int i; h2f h; };

__device__ __forceinline__ float leakyf_(float x){ return x>0.f ? x : 0.2f*x; }
__device__ __forceinline__ float fsig_(float x){ return 1.f/(1.f+__expf(-x)); }
__device__ __forceinline__ float ftanh_(float x){ float e=__expf(2.f*x); return 1.f-2.f/(e+1.f); }

// LDS-only barrier: waits LDS ops, does NOT drain vmcnt.
#define BARRIER_LDS() asm volatile("s_waitcnt lgkmcnt(0)\n\ts_barrier" ::: "memory")
#define WAIT_VM0()    asm volatile("s_waitcnt vmcnt(0)" ::: "memory")

// agent-scope (device) atomic helpers for cross-block streams
__device__ __forceinline__ float ld_agent(const float* p) {
  return __hip_atomic_load(p, __ATOMIC_RELAXED, __HIP_MEMORY_SCOPE_AGENT);
}
__device__ __forceinline__ void st_agent(float* p, float v) {
  __hip_atomic_store(p, v, __ATOMIC_RELAXED, __HIP_MEMORY_SCOPE_AGENT);
}
__device__ __forceinline__ unsigned ld_agent_u32(const unsigned* p) {
  return __hip_atomic_load(p, __ATOMIC_RELAXED, __HIP_MEMORY_SCOPE_AGENT);
}
__device__ __forceinline__ void st_agent_u32(unsigned* p, unsigned v) {
  __hip_atomic_store(p, v, __ATOMIC_RELAXED, __HIP_MEMORY_SCOPE_AGENT);
}
__device__ __forceinline__ int ld_ctr(const int* p) {
  return __hip_atomic_load(p, __ATOMIC_ACQUIRE, __HIP_MEMORY_SCOPE_AGENT);
}
__device__ __forceinline__ void st_ctr(int* p, int v) {
  __hip_atomic_store(p, v, __ATOMIC_RELEASE, __HIP_MEMORY_SCOPE_AGENT);
}

// ---------------------------------------------------------------------------
// Generic tiled fp32 GEMM.  C[m,n] = sum_k A[m,k] * (TB ? B[n,k] : B[k,n]) + bias[n]
// ---------------------------------------------------------------------------
template<bool TB>
__global__ __launch_bounds__(256) void gemm_k(const float* __restrict__ A,
                                              const float* __restrict__ B,
                                              const float* __restrict__ bias,
                                              float* __restrict__ C,
                                              int M, int N, int K) {
  __shared__ float As[16][65];
  __shared__ float Bs[16][65];
  const int bm = blockIdx.x * 64, bn = blockIdx.y * 64;
  const int tid = threadIdx.x;
  const int tm = (tid >> 4) << 2, tn = (tid & 15) << 2;
  float acc[4][4] = {};
  const int row = tid & 63, kq = (tid >> 6) << 2;
  for (int k0 = 0; k0 < K; k0 += 16) {
    float4 av = make_float4(0.f, 0.f, 0.f, 0.f);
    const int m = bm + row;
    if (m < M) av = *(const float4*)(A + (size_t)m * K + k0 + kq);
    As[kq + 0][row] = av.x; As[kq + 1][row] = av.y;
    As[kq + 2][row] = av.z; As[kq + 3][row] = av.w;
    if (TB) {
      float4 bv = *(const float4*)(B + (size_t)(bn + row) * K + k0 + kq);
      Bs[kq + 0][row] = bv.x; Bs[kq + 1][row] = bv.y;
      Bs[kq + 2][row] = bv.z; Bs[kq + 3][row] = bv.w;
    } else {
      const int kr = tid >> 4, nq = (tid & 15) << 2;
      float4 bv = *(const float4*)(B + (size_t)(k0 + kr) * N + bn + nq);
      Bs[kr][nq + 0] = bv.x; Bs[kr][nq + 1] = bv.y;
      Bs[kr][nq + 2] = bv.z; Bs[kr][nq + 3] = bv.w;
    }
    __syncthreads();
#pragma unroll
    for (int kk = 0; kk < 16; kk++) {
      float a[4], b[4];
#pragma unroll
      for (int i = 0; i < 4; i++) a[i] = As[kk][tm + i];
#pragma unroll
      for (int j = 0; j < 4; j++) b[j] = Bs[kk][tn + j];
#pragma unroll
      for (int i = 0; i < 4; i++)
#pragma unroll
        for (int j = 0; j < 4; j++) acc[i][j] = fmaf(a[i], b[j], acc[i][j]);
    }
    __syncthreads();
  }
#pragma unroll
  for (int i = 0; i < 4; i++) {
    const int m = bm + tm + i;
    if (m < M) {
#pragma unroll
      for (int j = 0; j < 4; j++) {
        const int n = bn + tn + j;
        float v = acc[i][j];
        if (bias) v += bias[n];
        C[(size_t)m * N + n] = v;
      }
    }
  }
}

// ---------------------------------------------------------------------------
// Pipelined two-layer GRU across 4 CUs.  4 blocks x 256 threads.
// NEW in r12: h broadcast via v_readlane in-register instead of LDS re-reads.
// The whole h vector (128 fp16) fits in ONE VGPR/wave (lane l = pair
// h[2l:2l+1]); each wave loads it once per step (1 ds_read_b32, 2-way-free)
// and the dot loop broadcasts pairs with readlane (wave-uniform index).
// LDS pipe traffic/step: ~45 wave-instrs -> ~13.  Factories readlane
// directly off global-loaded h0 pairs (no LDS staging at all).
// ---------------------------------------------------------------------------
__global__ __launch_bounds__(256, 1) void gru_pipe(const float* __restrict__ gi0,
                                                   const float* __restrict__ w_hh0,
                                                   const float* __restrict__ b_hh0,
                                                   const float* __restrict__ w_ih1,
                                                   const float* __restrict__ b_ih1,
                                                   const float* __restrict__ w_hh1,
                                                   const float* __restrict__ b_hh1,
                                                   unsigned* h0_st16, float* gi1_st,
                                                   int* ctr,           // [0]=prog0 [1]=pf0 [2]=pf1
                                                   float* __restrict__ h1_out,
                                                   int T) {
  __shared__ _Float16 hbuf[2][HID];    // packed fp16 h, double-buffered
  __shared__ float psum[3][HID];

  const int bid   = blockIdx.x;
  const int tid   = threadIdx.x;
  const int lane  = tid & 63;
  const int khalf = (tid >> 6) & 1;            // wave-uniform
  const int j     = (tid & 63) | ((tid >> 7) << 6);
  const int kbase = khalf * 64;                // fp16-element offset of K-half
  const int base32 = __builtin_amdgcn_readfirstlane(khalf * 32); // pair index base

  const float* wsrc = (bid == 0) ? w_hh0 : (bid == 3 ? w_hh1 : w_ih1);
  const float* bsrc = (bid == 0) ? b_hh0 : (bid == 3 ? b_hh1 : b_ih1);

  // load + convert this thread's half-rows of the 3 gates to packed fp16
  h2f wr[32], wz[32], wn[32];
#pragma unroll
  for (int i = 0; i < 16; i++) {
    float4 a = *(const float4*)(wsrc + (size_t)j * HID + kbase + i * 4);
    wr[2 * i]     = h2f{(_Float16)a.x, (_Float16)a.y};
    wr[2 * i + 1] = h2f{(_Float16)a.z, (_Float16)a.w};
  }
#pragma unroll
  for (int i = 0; i < 16; i++) {
    float4 a = *(const float4*)(wsrc + (size_t)(j + HID) * HID + kbase + i * 4);
    wz[2 * i]     = h2f{(_Float16)a.x, (_Float16)a.y};
    wz[2 * i + 1] = h2f{(_Float16)a.z, (_Float16)a.w};
  }
#pragma unroll
  for (int i = 0; i < 16; i++) {
    float4 a = *(const float4*)(wsrc + (size_t)(j + 2 * HID) * HID + kbase + i * 4);
    wn[2 * i]     = h2f{(_Float16)a.x, (_Float16)a.y};
    wn[2 * i + 1] = h2f{(_Float16)a.z, (_Float16)a.w};
  }
  const float b0 = bsrc[j];
  const float b1 = bsrc[j + HID];
  const float b2 = bsrc[j + 2 * HID];

  // dot via readlane broadcast of packed h pairs (hreg: lane l = h[2l:2l+1])
  auto dot_bcast = [&](int hreg, float& r, float& z, float& n) {
    float ar0 = 0.f, ar1 = 0.f, az0 = 0.f, az1 = 0.f, an0 = 0.f, an1 = 0.f;
#pragma unroll
    for (int k = 0; k < 32; k++) {
      UI2H u; u.i = __builtin_amdgcn_readlane(hreg, base32 + k);
      const h2f hh = u.h;
      if (k & 1) {
        ar1 = __builtin_amdgcn_fdot2(wr[k], hh, ar1, false);
        az1 = __builtin_amdgcn_fdot2(wz[k], hh, az1, false);
        an1 = __builtin_amdgcn_fdot2(wn[k], hh, an1, false);
      } else {
        ar0 = __builtin_amdgcn_fdot2(wr[k], hh, ar0, false);
        az0 = __builtin_amdgcn_fdot2(wz[k], hh, az0, false);
        an0 = __builtin_amdgcn_fdot2(wn[k], hh, an0, false);
      }
    }
    r = ar0 + ar1; z = az0 + az1; n = an0 + an1;
  };

  if (bid == 0 || bid == 3) {
    // ---------------- scan roles (bid0 = layer-0, bid3 = layer-1) -----------
    const float* gsrc = (bid == 0) ? gi0 : gi1_st;
    float hcur = 0.f;
    int hreg = 0;                              // h starts at zero
    if (tid < 64) ((int*)&hbuf[0][0])[tid] = 0;
    BARRIER_LDS();

    if (bid == 3 && tid == 0) {            // ensure gi1[0..3] published
      while (ld_ctr(&ctr[1]) < 4) {}
      while (ld_ctr(&ctr[2]) < 4) {}
    }
    if (bid == 3) __syncthreads();

    // four independent prefetch register sets (t mod 4 = 0,1,2,3)
    float gxA, gyA, gzA, gxB, gyB, gzB, gxC, gyC, gzC, gxD, gyD, gzD;
    if (khalf == 0) {
      const float* gp = gsrc + j;
      gxA = gp[0]; gyA = gp[HID]; gzA = gp[2 * HID];
      gp = gsrc + (size_t)1 * G3 + j;
      gxB = gp[0]; gyB = gp[HID]; gzB = gp[2 * HID];
      gp = gsrc + (size_t)2 * G3 + j;
      gxC = gp[0]; gyC = gp[HID]; gzC = gp[2 * HID];
      gp = gsrc + (size_t)3 * G3 + j;
      gxD = gp[0]; gyD = gp[HID]; gzD = gp[2 * HID];
    }

    auto substep = [&](int tc, int pin, float& gx, float& gy, float& gz) {
      float dr, dz, dn;
      dot_bcast(hreg, dr, dz, dn);
      if (khalf == 1) { psum[0][j] = dr; psum[1][j] = dz; psum[2][j] = dn; }
      BARRIER_LDS();
      if (khalf == 0) {
        const float r = fsig_(gx + b0 + dr + psum[0][j]);
        const float z = fsig_(gy + b1 + dz + psum[1][j]);
        const float n = ftanh_(gz + r * (b2 + dn + psum[2][j]));
        hcur = (1.f - z) * n + z * hcur;
        hbuf[pin ^ 1][j] = (_Float16)hcur;
        if (bid == 3) h1_out[(size_t)tc * HID + j] = hcur;
        // reload this gi set for tc+4 (consumed 4 sub-steps later)
        const int tp = (tc + 4 < T) ? (tc + 4) : 0;
        const float* gp = gsrc + (size_t)tp * G3 + j;
        gx = gp[0]; gy = gp[HID]; gz = gp[2 * HID];
      }
      // consumer: poll once per 32 steps, deep margin (amortized LLC spin)
      if (bid == 3 && tid == 0 && (tc & 31) == 0) {
        int need = tc + 36; if (need > T) need = T;
        while (ld_ctr(&ctr[1]) < need) {}
        while (ld_ctr(&ctr[2]) < need) {}
      }
      BARRIER_LDS();
      // every wave re-arms its h broadcast register for the next step
      hreg = ((const int*)&hbuf[pin ^ 1][0])[lane];
      // producer: wave 1 (stores only in its vmcnt) exports fp16 h0[tc]
      // directly from hreg (its lanes hold exactly pairs h[2l:2l+1])
      if (bid == 0 && tid >= 64 && tid < 128) {
        st_agent_u32(&h0_st16[(size_t)tc * 64 + lane], (unsigned)hreg);
        if ((tc & 7) == 7) {
          WAIT_VM0();                        // drains only wave-1 stores
          if (tid == 64) st_ctr(&ctr[0], tc + 1);
        }
      }
    };

    for (int t = 0; t < T; t += 4) {
      substep(t,     0, gxA, gyA, gzA);
      substep(t + 1, 1, gxB, gyB, gzB);
      substep(t + 2, 0, gxC, gyC, gzC);
      substep(t + 3, 1, gxD, gyD, gzD);
    }
    if (bid == 0 && tid >= 64 && tid < 128) {  // final publish
      WAIT_VM0();
      if (tid == 64) st_ctr(&ctr[0], T);
    }
  } else {
    // ---------------- factory roles (gi1 for parity f), BATCHED -------------
    // No LDS h staging: every thread loads the packed h0 pairs from global
    // (lane l = pair h0[2l:2l+1]) and the dot readlane-broadcasts in-register.
    const int f = bid - 1;                    // 0 or 1
    for (int t0 = f; t0 < T; t0 += 8) {       // batch: t0, t0+2, t0+4, t0+6
      if (tid == 0) {
        int need = t0 + 7; if (need > T) need = T;
        while (ld_ctr(&ctr[0]) < need) {}
      }
      __syncthreads();
      // prefetch all 4 h0 vectors for this batch into registers (all waves)
      int hv0 = 0, hv1 = 0, hv2 = 0, hv3 = 0;
      hv0 = (int)ld_agent_u32(&h0_st16[(size_t)t0 * 64 + lane]);
      if (t0 + 2 < T) hv1 = (int)ld_agent_u32(&h0_st16[(size_t)(t0 + 2) * 64 + lane]);
      if (t0 + 4 < T) hv2 = (int)ld_agent_u32(&h0_st16[(size_t)(t0 + 4) * 64 + lane]);
      if (t0 + 6 < T) hv3 = (int)ld_agent_u32(&h0_st16[(size_t)(t0 + 6) * 64 + lane]);
#pragma unroll
      for (int k = 0; k < 4; k++) {
        const int t = t0 + 2 * k;
        if (t >= T) break;
        const int hv = (k == 0) ? hv0 : (k == 1) ? hv1 : (k == 2) ? hv2 : hv3;
        float dr, dz, dn;
        dot_bcast(hv, dr, dz, dn);
        if (khalf == 1) { psum[0][j] = dr; psum[1][j] = dz; psum[2][j] = dn; }
        BARRIER_LDS();
        if (khalf == 0) {
          float* gp = gi1_st + (size_t)t * G3 + j;
          st_agent(gp,           dr + psum[0][j] + b0);
          st_agent(gp + HID,     dz + psum[1][j] + b1);
          st_agent(gp + 2 * HID, dn + psum[2][j] + b2);
        }
        BARRIER_LDS();                        // protect psum WAR
      }
      __syncthreads();                        // drain gi1 stores (all waves)
      if (tid == 0) {
        int pub = t0 + 8; if (pub > T) pub = T;
        st_ctr(&ctr[1 + f], pub);
      }
    }
    __syncthreads();
    if (tid == 0) st_ctr(&ctr[1 + f], T);
  }
}

// ---------------------------------------------------------------------------
// Attention per-node dots: a_s[n,h] = feat[n,h,:].att_src[h,:]  (same for dst)
// ---------------------------------------------------------------------------
__global__ void att_dots(const float* __restrict__ feat,
                         const float* __restrict__ att_src,
                         const float* __restrict__ att_dst,
                         float* __restrict__ a_s, float* __restrict__ a_d,
                         int heads, int C) {
  const int n = blockIdx.x;
  const int h = threadIdx.x >> 6;
  const int lane = threadIdx.x & 63;
  float ss = 0.f, dd = 0.f;
  const float* f = feat + (size_t)n * heads * C + h * C;
  for (int c = lane; c < C; c += 64) {
    const float v = f[c];
    ss = fmaf(v, att_src[h * C + c], ss);
    dd = fmaf(v, att_dst[h * C + c], dd);
  }
#pragma unroll
  for (int o = 32; o > 0; o >>= 1) {
    ss += __shfl_down(ss, o);
    dd += __shfl_down(dd, o);
  }
  if (lane == 0) { a_s[n * heads + h] = ss; a_d[n * heads + h] = dd; }
}

// ---------------------------------------------------------------------------
// CSR build (edge_index arrives as int32: ei[0..E) = src, ei[E..2E) = dst)
// ---------------------------------------------------------------------------
__global__ void edge_count(const int* __restrict__ ei, int* __restrict__ cnt, int E) {
  const int e = blockIdx.x * 256 + threadIdx.x;
  if (e < E) atomicAdd(&cnt[ei[E + e]], 1);
}

__global__ __launch_bounds__(1024) void prefix_scan(const int* __restrict__ cnt,
                                                    int* __restrict__ offs,
                                                    int* __restrict__ cursor, int N) {
  __shared__ int buf[1024];
  __shared__ int carry;
  const int tid = threadIdx.x;
  if (tid == 0) carry = 0;
  __syncthreads();
  for (int base = 0; base < N; base += 1024) {
    const int i = base + tid;
    const int v = (i < N) ? cnt[i] : 0;
    buf[tid] = v;
    __syncthreads();
    for (int d = 1; d < 1024; d <<= 1) {
      int t = 0;
      if (tid >= d) t = buf[tid - d];
      __syncthreads();
      buf[tid] += t;
      __syncthreads();
    }
    const int incl = buf[tid] + carry;
    if (i < N) { offs[i] = incl - v; cursor[i] = incl - v; }
    __syncthreads();
    if (tid == 1023) carry = incl;
    __syncthreads();
  }
  if (tid == 0) offs[N] = carry;
}

__global__ void edge_fill(const int* __restrict__ ei, int* __restrict__ cursor,
                          int* __restrict__ csr, int E) {
  const int e = blockIdx.x * 256 + threadIdx.x;
  if (e < E) {
    const int d = ei[E + e];
    const int s = ei[e];
    const int pos = atomicAdd(&cursor[d], 1);
    csr[pos] = s;
  }
}

// ---------------------------------------------------------------------------
// GAT softmax-aggregation.  One block per dst node; blockDim = heads<<cshift.
// ---------------------------------------------------------------------------
__global__ void gat_agg(const float* __restrict__ feat,
                        const float* __restrict__ a_s, const float* __restrict__ a_d,
                        const int* __restrict__ offs, const int* __restrict__ csr,
                        const float* __restrict__ bias, float* __restrict__ out,
                        int heads, int cshift, int do_relu) {
  const int n = blockIdx.x;
  const int t = threadIdx.x;
  const int HC = blockDim.x;
  const int h = t >> cshift;
  const int beg = offs[n], end = offs[n + 1];
  const float ad = a_d[n * heads + h];
  const float self_e = leakyf_(a_s[n * heads + h] + ad);
  float m = self_e;
  for (int i = beg; i < end; i++) {
    const int s = csr[i];
    m = fmaxf(m, leakyf_(a_s[s * heads + h] + ad));
  }
  float den = expf(self_e - m);
  float acc = den * feat[(size_t)n * HC + t];
  for (int i = beg; i < end; i++) {
    const int s = csr[i];
    const float wgt = expf(leakyf_(a_s[s * heads + h] + ad) - m);
    den += wgt;
    acc = fmaf(wgt, feat[(size_t)s * HC + t], acc);
  }
  float o = acc / den + bias[t];
  if (do_relu) o = fmaxf(o, 0.f);
  out[(size_t)n * HC + t] = o;
}

// ---------------------------------------------------------------------------
extern "C" void kernel_launch(void* const* d_in, const int* in_sizes, int n_in,
                              void* d_out, int out_size, void* d_ws, size_t ws_size,
                              hipStream_t stream) {
  const float* x        = (const float*)d_in[0];
  const int*   ei       = (const int*)d_in[1];   // int64 inputs arrive as int32
  const float* w_ih0    = (const float*)d_in[2];
  const float* w_hh0    = (const float*)d_in[3];
  const float* b_ih0    = (const float*)d_in[4];
  const float* b_hh0    = (const float*)d_in[5];
  const float* w_ih1    = (const float*)d_in[6];
  const float* w_hh1    = (const float*)d_in[7];
  const float* b_ih1    = (const float*)d_in[8];
  const float* b_hh1    = (const float*)d_in[9];
  const float* W1       = (const float*)d_in[10];
  const float* att_src1 = (const float*)d_in[11];
  const float* att_dst1 = (const float*)d_in[12];
  const float* bias1    = (const float*)d_in[13];
  const float* W2       = (const float*)d_in[14];
  const float* att_src2 = (const float*)d_in[15];
  const float* att_dst2 = (const float*)d_in[16];
  const float* bias2    = (const float*)d_in[17];
  float* out = (float*)d_out;

  const int N = NN_;
  const int E = in_sizes[1] / 2;

  // ---- workspace layout with overlays (peak ~54 MB) ----
  float* f    = (float*)d_ws;
  float* gi   = f;                         // region A (gi0; dead after scan)
  float* hmm1 = f;                         // = A, reused for GAT1 features
  float* h1   = f + (size_t)N * HC1;                    // B
  float* g1o  = h1 + (size_t)N * HID;                   // C (post-scan)
  float* hmm2 = g1o + (size_t)N * HC1;                  // D
  float* as1  = hmm2 + (size_t)N * OUTD;
  float* ad1  = as1 + (size_t)N * 4;
  float* as2  = ad1 + (size_t)N * 4;
  float* ad2  = as2 + (size_t)N;
  int* cnt    = (int*)(ad2 + (size_t)N);
  int* offs   = cnt + N;        // N+1
  int* cursor = offs + (N + 1);
  int* csr    = cursor + N;     // E
  int* ctr    = csr + E;        // 3 ints: prog0, pf0, pf1
  // scan-time streams overlay region C (g1o): N*64 uints (fp16 h0) + N*G3
  // floats (gi1) = N*448 float-slots <= N*HC1 ✓
  unsigned* h0_st16 = (unsigned*)g1o;
  float*    gi1_st  = g1o + (size_t)N * 64;

  const int mblocks = (N + 63) / 64;

  // GRU: gi0 GEMM, zero counters, then 4-CU pipelined two-layer scan
  gemm_k<true><<<dim3(mblocks, G3 / 64), 256, 0, stream>>>(x, w_ih0, b_ih0, gi, N, G3, IND);
  hipMemsetAsync(ctr, 0, 3 * sizeof(int), stream);
  gru_pipe<<<4, 256, 0, stream>>>(gi, w_hh0, b_hh0, w_ih1, b_ih1, w_hh1, b_hh1,
                                  h0_st16, gi1_st, ctr, h1, N);

  // CSR by dst (shared by both GAT layers)
  hipMemsetAsync(cnt, 0, (size_t)N * sizeof(int), stream);
  edge_count<<<(E + 255) / 256, 256, 0, stream>>>(ei, cnt, E);
  prefix_scan<<<1, 1024, 0, stream>>>(cnt, offs, cursor, N);
  edge_fill<<<(E + 255) / 256, 256, 0, stream>>>(ei, cursor, csr, E);

  // GAT layer 1
  gemm_k<false><<<dim3(mblocks, HC1 / 64), 256, 0, stream>>>(h1, W1, nullptr, hmm1, N, HC1, HID);
  att_dots<<<N, 4 * 64, 0, stream>>>(hmm1, att_src1, att_dst1, as1, ad1, 4, HID);
  gat_agg<<<N, HC1, 0, stream>>>(hmm1, as1, ad1, offs, csr, bias1, g1o, 4, 7, 1);

  // GAT layer 2
  gemm_k<false><<<dim3(mblocks, OUTD / 64), 256, 0, stream>>>(g1o, W2, nullptr, hmm2, N, OUTD, HC1);
  att_dots<<<N, 1 * 64, 0, stream>>>(hmm2, att_src2, att_dst2, as2, ad2, 1, OUTD);
  gat_agg<<<N, OUTD, 0, stream>>>(hmm2, as2, ad2, offs, csr, bias2, out, 1, 6, 0);
}

// Round 13
// 6294.775 us; speedup vs baseline: 1.1280x; 1.1280x over previous
//
#include <hip/hip_runtime.h>
#include <math.h>

#define NN_  10000
#define NE_  320000
#define IND  64
#define HID  128
#define G3   384   // 3*HID
#define HC1  512   // 4 heads * 128
#define OUTD 64

#define CSR_CNT_BLKS 40
#define CSR_FILL_BLKS 40

typedef _Float16 h2f __attribute__((ext_vector_type(2)));
union UH4 { uint4 u; h2f h[4]; };

__device__ __forceinline__ float leakyf_(float x){ return x>0.f ? x : 0.2f*x; }
__device__ __forceinline__ float fsig_(float x){ return 1.f/(1.f+__expf(-x)); }
__device__ __forceinline__ float ftanh_(float x){ float e=__expf(2.f*x); return 1.f-2.f/(e+1.f); }

// LDS-only barrier: waits LDS ops, does NOT drain vmcnt.
#define BARRIER_LDS() asm volatile("s_waitcnt lgkmcnt(0)\n\ts_barrier" ::: "memory")
#define WAIT_VM0()    asm volatile("s_waitcnt vmcnt(0)" ::: "memory")

// agent-scope (device) atomic helpers for cross-block streams
__device__ __forceinline__ float ld_agent(const float* p) {
  return __hip_atomic_load(p, __ATOMIC_RELAXED, __HIP_MEMORY_SCOPE_AGENT);
}
__device__ __forceinline__ void st_agent(float* p, float v) {
  __hip_atomic_store(p, v, __ATOMIC_RELAXED, __HIP_MEMORY_SCOPE_AGENT);
}
__device__ __forceinline__ unsigned ld_agent_u32(const unsigned* p) {
  return __hip_atomic_load(p, __ATOMIC_RELAXED, __HIP_MEMORY_SCOPE_AGENT);
}
__device__ __forceinline__ void st_agent_u32(unsigned* p, unsigned v) {
  __hip_atomic_store(p, v, __ATOMIC_RELAXED, __HIP_MEMORY_SCOPE_AGENT);
}
__device__ __forceinline__ int ld_ctr(const int* p) {
  return __hip_atomic_load(p, __ATOMIC_ACQUIRE, __HIP_MEMORY_SCOPE_AGENT);
}
__device__ __forceinline__ void st_ctr(int* p, int v) {
  __hip_atomic_store(p, v, __ATOMIC_RELEASE, __HIP_MEMORY_SCOPE_AGENT);
}

// ---------------------------------------------------------------------------
// Generic tiled fp32 GEMM.  C[m,n] = sum_k A[m,k] * (TB ? B[n,k] : B[k,n]) + bias[n]
// ---------------------------------------------------------------------------
template<bool TB>
__global__ __launch_bounds__(256) void gemm_k(const float* __restrict__ A,
                                              const float* __restrict__ B,
                                              const float* __restrict__ bias,
                                              float* __restrict__ C,
                                              int M, int N, int K) {
  __shared__ float As[16][65];
  __shared__ float Bs[16][65];
  const int bm = blockIdx.x * 64, bn = blockIdx.y * 64;
  const int tid = threadIdx.x;
  const int tm = (tid >> 4) << 2, tn = (tid & 15) << 2;
  float acc[4][4] = {};
  const int row = tid & 63, kq = (tid >> 6) << 2;
  for (int k0 = 0; k0 < K; k0 += 16) {
    float4 av = make_float4(0.f, 0.f, 0.f, 0.f);
    const int m = bm + row;
    if (m < M) av = *(const float4*)(A + (size_t)m * K + k0 + kq);
    As[kq + 0][row] = av.x; As[kq + 1][row] = av.y;
    As[kq + 2][row] = av.z; As[kq + 3][row] = av.w;
    if (TB) {
      float4 bv = *(const float4*)(B + (size_t)(bn + row) * K + k0 + kq);
      Bs[kq + 0][row] = bv.x; Bs[kq + 1][row] = bv.y;
      Bs[kq + 2][row] = bv.z; Bs[kq + 3][row] = bv.w;
    } else {
      const int kr = tid >> 4, nq = (tid & 15) << 2;
      float4 bv = *(const float4*)(B + (size_t)(k0 + kr) * N + bn + nq);
      Bs[kr][nq + 0] = bv.x; Bs[kr][nq + 1] = bv.y;
      Bs[kr][nq + 2] = bv.z; Bs[kr][nq + 3] = bv.w;
    }
    __syncthreads();
#pragma unroll
    for (int kk = 0; kk < 16; kk++) {
      float a[4], b[4];
#pragma unroll
      for (int i = 0; i < 4; i++) a[i] = As[kk][tm + i];
#pragma unroll
      for (int j = 0; j < 4; j++) b[j] = Bs[kk][tn + j];
#pragma unroll
      for (int i = 0; i < 4; i++)
#pragma unroll
        for (int j = 0; j < 4; j++) acc[i][j] = fmaf(a[i], b[j], acc[i][j]);
    }
    __syncthreads();
  }
#pragma unroll
  for (int i = 0; i < 4; i++) {
    const int m = bm + tm + i;
    if (m < M) {
#pragma unroll
      for (int j = 0; j < 4; j++) {
        const int n = bn + tn + j;
        float v = acc[i][j];
        if (bias) v += bias[n];
        C[(size_t)m * N + n] = v;
      }
    }
  }
}

// ---------------------------------------------------------------------------
// Pipelined two-layer GRU across 4 CUs (r11 scan core) + CSR build folded in.
//  block 0: layer-0 scan -> fp16 h0 stream + progress ctr every 8 steps
//  blocks 1,2: gi1 factories (parity-split), BATCHED (poll once per 4 items)
//  block 3: layer-1 scan consuming gi1; polls ctrs once per 32 steps
//  blocks 4..: CSR-by-dst build (independent of GRU, overlaps the scan):
//    4..43  edge_count (grid-stride atomics) -> ctr[3] done-counter
//    44     prefix scan (acquire ctr[3]==40, 256-thread scan, fence, ctr[4]=1)
//    45..84 edge_fill (acquire ctr[4], s_sleep backoff, cursor atomics)
// ctr: [0]=prog0 [1]=pf0 [2]=pf1 [3]=count_done [4]=prefix_done [5]=pad
// ---------------------------------------------------------------------------
__global__ __launch_bounds__(256, 1) void gru_pipe(const float* __restrict__ gi0,
                                                   const float* __restrict__ w_hh0,
                                                   const float* __restrict__ b_hh0,
                                                   const float* __restrict__ w_ih1,
                                                   const float* __restrict__ b_ih1,
                                                   const float* __restrict__ w_hh1,
                                                   const float* __restrict__ b_hh1,
                                                   unsigned* h0_st16, float* gi1_st,
                                                   int* ctr,
                                                   float* __restrict__ h1_out,
                                                   int T,
                                                   const int* __restrict__ ei,
                                                   int* cnt, int* offs,
                                                   int* cursor, int* csr, int E) {
  __shared__ _Float16 hbuf[2][HID];
  __shared__ float psum[3][HID];
  __shared__ int sbuf[256];
  __shared__ int scarry;

  const int bid   = blockIdx.x;
  const int tid   = threadIdx.x;

  // ======================= CSR roles (bid >= 4) ==========================
  if (bid >= 4) {
    const int cb = bid - 4;
    if (cb < CSR_CNT_BLKS) {
      for (int e = cb * 256 + tid; e < E; e += CSR_CNT_BLKS * 256)
        atomicAdd(&cnt[ei[E + e]], 1);
      __syncthreads();
      if (tid == 0)
        __hip_atomic_fetch_add(&ctr[3], 1, __ATOMIC_RELEASE, __HIP_MEMORY_SCOPE_AGENT);
    } else if (cb == CSR_CNT_BLKS) {
      if (tid == 0) {
        while (ld_ctr(&ctr[3]) < CSR_CNT_BLKS) __builtin_amdgcn_s_sleep(32);
      }
      __syncthreads();
      if (tid == 0) scarry = 0;
      __syncthreads();
      for (int base = 0; base < NN_; base += 256) {
        const int i = base + tid;
        const int v = (i < NN_) ? cnt[i] : 0;
        sbuf[tid] = v;
        __syncthreads();
        for (int d = 1; d < 256; d <<= 1) {
          int t2 = 0;
          if (tid >= d) t2 = sbuf[tid - d];
          __syncthreads();
          sbuf[tid] += t2;
          __syncthreads();
        }
        const int incl = sbuf[tid] + scarry;
        if (i < NN_) { offs[i] = incl - v; cursor[i] = incl - v; }
        __syncthreads();
        if (tid == 255) scarry = incl;
        __syncthreads();
      }
      if (tid == 0) {
        offs[NN_] = scarry;
        __threadfence();
        st_ctr(&ctr[4], 1);
      }
    } else {
      const int fb = cb - CSR_CNT_BLKS - 1;   // 0..CSR_FILL_BLKS-1
      if (tid == 0) {
        while (ld_ctr(&ctr[4]) < 1) __builtin_amdgcn_s_sleep(64);
      }
      __syncthreads();
      for (int e = fb * 256 + tid; e < E; e += CSR_FILL_BLKS * 256) {
        const int d = ei[E + e];
        const int s = ei[e];
        const int pos = atomicAdd(&cursor[d], 1);
        csr[pos] = s;
      }
    }
    return;
  }

  // ======================= GRU roles (bid 0..3, r11 core) ================
  const int lane  = tid & 63;
  const int khalf = (tid >> 6) & 1;
  const int j     = (tid & 63) | ((tid >> 7) << 6);
  const int kbase = khalf * 64;

  const float* wsrc = (bid == 0) ? w_hh0 : (bid == 3 ? w_hh1 : w_ih1);
  const float* bsrc = (bid == 0) ? b_hh0 : (bid == 3 ? b_hh1 : b_ih1);

  // load + convert this thread's half-rows of the 3 gates to packed fp16
  h2f wr[32], wz[32], wn[32];
#pragma unroll
  for (int i = 0; i < 16; i++) {
    float4 a = *(const float4*)(wsrc + (size_t)j * HID + kbase + i * 4);
    wr[2 * i]     = h2f{(_Float16)a.x, (_Float16)a.y};
    wr[2 * i + 1] = h2f{(_Float16)a.z, (_Float16)a.w};
  }
#pragma unroll
  for (int i = 0; i < 16; i++) {
    float4 a = *(const float4*)(wsrc + (size_t)(j + HID) * HID + kbase + i * 4);
    wz[2 * i]     = h2f{(_Float16)a.x, (_Float16)a.y};
    wz[2 * i + 1] = h2f{(_Float16)a.z, (_Float16)a.w};
  }
#pragma unroll
  for (int i = 0; i < 16; i++) {
    float4 a = *(const float4*)(wsrc + (size_t)(j + 2 * HID) * HID + kbase + i * 4);
    wn[2 * i]     = h2f{(_Float16)a.x, (_Float16)a.y};
    wn[2 * i + 1] = h2f{(_Float16)a.z, (_Float16)a.w};
  }
  const float b0 = bsrc[j];
  const float b1 = bsrc[j + HID];
  const float b2 = bsrc[j + 2 * HID];

  // dot over this thread's K-half from an LDS fp16 vector at 'hp16'
  auto dot_half = [&](const _Float16* hp16, float& r, float& z, float& n) {
    const uint4* hp = (const uint4*)(hp16 + kbase);
    float ar0 = 0.f, ar1 = 0.f, az0 = 0.f, az1 = 0.f, an0 = 0.f, an1 = 0.f;
#pragma unroll
    for (int c = 0; c < 2; c++) {
      uint4 hv[4];
#pragma unroll
      for (int i = 0; i < 4; i++) hv[i] = hp[c * 4 + i];
#pragma unroll
      for (int i = 0; i < 4; i++) {
        UH4 v; v.u = hv[i];
#pragma unroll
        for (int q = 0; q < 4; q++) {
          const int k = c * 16 + i * 4 + q;
          const h2f hh = v.h[q];
          if (k & 1) {
            ar1 = __builtin_amdgcn_fdot2(wr[k], hh, ar1, false);
            az1 = __builtin_amdgcn_fdot2(wz[k], hh, az1, false);
            an1 = __builtin_amdgcn_fdot2(wn[k], hh, an1, false);
          } else {
            ar0 = __builtin_amdgcn_fdot2(wr[k], hh, ar0, false);
            az0 = __builtin_amdgcn_fdot2(wz[k], hh, az0, false);
            an0 = __builtin_amdgcn_fdot2(wn[k], hh, an0, false);
          }
        }
      }
    }
    r = ar0 + ar1; z = az0 + az1; n = an0 + an1;
  };

  if (bid == 0 || bid == 3) {
    // ---------------- scan roles (bid0 = layer-0, bid3 = layer-1) -----------
    const float* gsrc = (bid == 0) ? gi0 : gi1_st;
    float hcur = 0.f;
    if (khalf == 0) hbuf[0][j] = (_Float16)0.f;
    BARRIER_LDS();

    if (bid == 3 && tid == 0) {            // ensure gi1[0..3] published
      while (ld_ctr(&ctr[1]) < 4) {}
      while (ld_ctr(&ctr[2]) < 4) {}
    }
    if (bid == 3) __syncthreads();

    // four independent prefetch register sets (t mod 4 = 0,1,2,3)
    float gxA, gyA, gzA, gxB, gyB, gzB, gxC, gyC, gzC, gxD, gyD, gzD;
    if (khalf == 0) {
      const float* gp = gsrc + j;
      gxA = gp[0]; gyA = gp[HID]; gzA = gp[2 * HID];
      gp = gsrc + (size_t)1 * G3 + j;
      gxB = gp[0]; gyB = gp[HID]; gzB = gp[2 * HID];
      gp = gsrc + (size_t)2 * G3 + j;
      gxC = gp[0]; gyC = gp[HID]; gzC = gp[2 * HID];
      gp = gsrc + (size_t)3 * G3 + j;
      gxD = gp[0]; gyD = gp[HID]; gzD = gp[2 * HID];
    }

    auto substep = [&](int tc, int pin, float& gx, float& gy, float& gz) {
      float dr, dz, dn;
      dot_half(&hbuf[pin][0], dr, dz, dn);
      if (khalf == 1) { psum[0][j] = dr; psum[1][j] = dz; psum[2][j] = dn; }
      BARRIER_LDS();
      if (khalf == 0) {
        const float r = fsig_(gx + b0 + dr + psum[0][j]);
        const float z = fsig_(gy + b1 + dz + psum[1][j]);
        const float n = ftanh_(gz + r * (b2 + dn + psum[2][j]));
        hcur = (1.f - z) * n + z * hcur;
        hbuf[pin ^ 1][j] = (_Float16)hcur;
        if (bid == 3) h1_out[(size_t)tc * HID + j] = hcur;
        // reload this set for tc+4 (consumed 4 sub-steps later)
        const int tp = (tc + 4 < T) ? (tc + 4) : 0;
        const float* gp = gsrc + (size_t)tp * G3 + j;
        gx = gp[0]; gy = gp[HID]; gz = gp[2 * HID];
      }
      // consumer: poll once per 32 steps, deep margin (amortized LLC spin)
      if (bid == 3 && tid == 0 && (tc & 31) == 0) {
        int need = tc + 36; if (need > T) need = T;
        while (ld_ctr(&ctr[1]) < need) {}
        while (ld_ctr(&ctr[2]) < need) {}
      }
      BARRIER_LDS();
      // producer: wave 1 (stores only in its vmcnt) exports fp16 h0[tc]
      if (bid == 0 && tid >= 64 && tid < 128) {
        const int idx = tid - 64;
        unsigned v = *(const unsigned*)&hbuf[pin ^ 1][2 * idx];
        st_agent_u32(&h0_st16[(size_t)tc * 64 + idx], v);
        if ((tc & 7) == 7) {
          WAIT_VM0();                        // drains only wave-1 stores
          if (tid == 64) st_ctr(&ctr[0], tc + 1);
        }
      }
    };

    for (int t = 0; t < T; t += 4) {
      substep(t,     0, gxA, gyA, gzA);
      substep(t + 1, 1, gxB, gyB, gzB);
      substep(t + 2, 0, gxC, gyC, gzC);
      substep(t + 3, 1, gxD, gyD, gzD);
    }
    if (bid == 0 && tid >= 64 && tid < 128) {  // final publish
      WAIT_VM0();
      if (tid == 64) st_ctr(&ctr[0], T);
    }
  } else {
    // ---------------- factory roles (gi1 for parity f), BATCHED -------------
    const int f = bid - 1;                    // 0 or 1
    _Float16* hstage = &hbuf[0][0];           // single staging buffer
    for (int t0 = f; t0 < T; t0 += 8) {       // batch: t0, t0+2, t0+4, t0+6
      if (tid == 0) {
        int need = t0 + 7; if (need > T) need = T;
        while (ld_ctr(&ctr[0]) < need) {}
      }
      __syncthreads();
      // prefetch all 4 h0 vectors for this batch into registers
      unsigned hv0 = 0, hv1 = 0, hv2 = 0, hv3 = 0;
      if (tid < 64) {
        hv0 = ld_agent_u32(&h0_st16[(size_t)t0 * 64 + tid]);
        if (t0 + 2 < T) hv1 = ld_agent_u32(&h0_st16[(size_t)(t0 + 2) * 64 + tid]);
        if (t0 + 4 < T) hv2 = ld_agent_u32(&h0_st16[(size_t)(t0 + 4) * 64 + tid]);
        if (t0 + 6 < T) hv3 = ld_agent_u32(&h0_st16[(size_t)(t0 + 6) * 64 + tid]);
      }
#pragma unroll
      for (int k = 0; k < 4; k++) {
        const int t = t0 + 2 * k;
        if (t >= T) break;
        if (tid < 64) {
          const unsigned hv = (k == 0) ? hv0 : (k == 1) ? hv1 : (k == 2) ? hv2 : hv3;
          ((unsigned*)hstage)[tid] = hv;
        }
        BARRIER_LDS();
        float dr, dz, dn;
        dot_half(hstage, dr, dz, dn);
        if (khalf == 1) { psum[0][j] = dr; psum[1][j] = dz; psum[2][j] = dn; }
        BARRIER_LDS();
        if (khalf == 0) {
          float* gp = gi1_st + (size_t)t * G3 + j;
          st_agent(gp,           dr + psum[0][j] + b0);
          st_agent(gp + HID,     dz + psum[1][j] + b1);
          st_agent(gp + 2 * HID, dn + psum[2][j] + b2);
        }
      }
      __syncthreads();                        // drain gi1 stores (all waves)
      if (tid == 0) {
        int pub = t0 + 8; if (pub > T) pub = T;
        st_ctr(&ctr[1 + f], pub);
      }
    }
    __syncthreads();
    if (tid == 0) st_ctr(&ctr[1 + f], T);
  }
}

// ---------------------------------------------------------------------------
// Attention per-node dots: a_s[n,h] = feat[n,h,:].att_src[h,:]  (same for dst)
// ---------------------------------------------------------------------------
__global__ void att_dots(const float* __restrict__ feat,
                         const float* __restrict__ att_src,
                         const float* __restrict__ att_dst,
                         float* __restrict__ a_s, float* __restrict__ a_d,
                         int heads, int C) {
  const int n = blockIdx.x;
  const int h = threadIdx.x >> 6;
  const int lane = threadIdx.x & 63;
  float ss = 0.f, dd = 0.f;
  const float* f = feat + (size_t)n * heads * C + h * C;
  for (int c = lane; c < C; c += 64) {
    const float v = f[c];
    ss = fmaf(v, att_src[h * C + c], ss);
    dd = fmaf(v, att_dst[h * C + c], dd);
  }
#pragma unroll
  for (int o = 32; o > 0; o >>= 1) {
    ss += __shfl_down(ss, o);
    dd += __shfl_down(dd, o);
  }
  if (lane == 0) { a_s[n * heads + h] = ss; a_d[n * heads + h] = dd; }
}

// ---------------------------------------------------------------------------
// GAT softmax-aggregation.  One block per dst node; blockDim = heads<<cshift.
// ---------------------------------------------------------------------------
__global__ void gat_agg(const float* __restrict__ feat,
                        const float* __restrict__ a_s, const float* __restrict__ a_d,
                        const int* __restrict__ offs, const int* __restrict__ csr,
                        const float* __restrict__ bias, float* __restrict__ out,
                        int heads, int cshift, int do_relu) {
  const int n = blockIdx.x;
  const int t = threadIdx.x;
  const int HC = blockDim.x;
  const int h = t >> cshift;
  const int beg = offs[n], end = offs[n + 1];
  const float ad = a_d[n * heads + h];
  const float self_e = leakyf_(a_s[n * heads + h] + ad);
  float m = self_e;
  for (int i = beg; i < end; i++) {
    const int s = csr[i];
    m = fmaxf(m, leakyf_(a_s[s * heads + h] + ad));
  }
  float den = expf(self_e - m);
  float acc = den * feat[(size_t)n * HC + t];
  for (int i = beg; i < end; i++) {
    const int s = csr[i];
    const float wgt = expf(leakyf_(a_s[s * heads + h] + ad) - m);
    den += wgt;
    acc = fmaf(wgt, feat[(size_t)s * HC + t], acc);
  }
  float o = acc / den + bias[t];
  if (do_relu) o = fmaxf(o, 0.f);
  out[(size_t)n * HC + t] = o;
}

// ---------------------------------------------------------------------------
extern "C" void kernel_launch(void* const* d_in, const int* in_sizes, int n_in,
                              void* d_out, int out_size, void* d_ws, size_t ws_size,
                              hipStream_t stream) {
  const float* x        = (const float*)d_in[0];
  const int*   ei       = (const int*)d_in[1];   // int64 inputs arrive as int32
  const float* w_ih0    = (const float*)d_in[2];
  const float* w_hh0    = (const float*)d_in[3];
  const float* b_ih0    = (const float*)d_in[4];
  const float* b_hh0    = (const float*)d_in[5];
  const float* w_ih1    = (const float*)d_in[6];
  const float* w_hh1    = (const float*)d_in[7];
  const float* b_ih1    = (const float*)d_in[8];
  const float* b_hh1    = (const float*)d_in[9];
  const float* W1       = (const float*)d_in[10];
  const float* att_src1 = (const float*)d_in[11];
  const float* att_dst1 = (const float*)d_in[12];
  const float* bias1    = (const float*)d_in[13];
  const float* W2       = (const float*)d_in[14];
  const float* att_src2 = (const float*)d_in[15];
  const float* att_dst2 = (const float*)d_in[16];
  const float* bias2    = (const float*)d_in[17];
  float* out = (float*)d_out;

  const int N = NN_;
  const int E = in_sizes[1] / 2;

  // ---- workspace layout with overlays (peak ~54 MB) ----
  float* f    = (float*)d_ws;
  float* gi   = f;                         // region A (gi0; dead after scan)
  float* hmm1 = f;                         // = A, reused for GAT1 features
  float* h1   = f + (size_t)N * HC1;                    // B
  float* g1o  = h1 + (size_t)N * HID;                   // C (post-scan)
  float* hmm2 = g1o + (size_t)N * HC1;                  // D
  float* as1  = hmm2 + (size_t)N * OUTD;
  float* ad1  = as1 + (size_t)N * 4;
  float* as2  = ad1 + (size_t)N * 4;
  float* ad2  = as2 + (size_t)N;
  int* cnt    = (int*)(ad2 + (size_t)N);
  int* offs   = cnt + N;        // N+1
  int* cursor = offs + (N + 1);
  int* csr    = cursor + N;     // E
  int* ctr    = csr + E;        // 6 ints
  // scan-time streams overlay region C (g1o): N*64 uints (fp16 h0) + N*G3
  // floats (gi1) = N*448 float-slots <= N*HC1 ✓
  unsigned* h0_st16 = (unsigned*)g1o;
  float*    gi1_st  = g1o + (size_t)N * 64;

  const int mblocks = (N + 63) / 64;

  // GRU: gi0 GEMM, zero counters+cnt, then pipelined scan + CSR build (fused)
  gemm_k<true><<<dim3(mblocks, G3 / 64), 256, 0, stream>>>(x, w_ih0, b_ih0, gi, N, G3, IND);
  hipMemsetAsync(ctr, 0, 6 * sizeof(int), stream);
  hipMemsetAsync(cnt, 0, (size_t)N * sizeof(int), stream);
  gru_pipe<<<4 + CSR_CNT_BLKS + 1 + CSR_FILL_BLKS, 256, 0, stream>>>(
      gi, w_hh0, b_hh0, w_ih1, b_ih1, w_hh1, b_hh1,
      h0_st16, gi1_st, ctr, h1, N, ei, cnt, offs, cursor, csr, E);

  // GAT layer 1
  gemm_k<false><<<dim3(mblocks, HC1 / 64), 256, 0, stream>>>(h1, W1, nullptr, hmm1, N, HC1, HID);
  att_dots<<<N, 4 * 64, 0, stream>>>(hmm1, att_src1, att_dst1, as1, ad1, 4, HID);
  gat_agg<<<N, HC1, 0, stream>>>(hmm1, as1, ad1, offs, csr, bias1, g1o, 4, 7, 1);

  // GAT layer 2
  gemm_k<false><<<dim3(mblocks, OUTD / 64), 256, 0, stream>>>(g1o, W2, nullptr, hmm2, N, OUTD, HC1);
  att_dots<<<N, 1 * 64, 0, stream>>>(hmm2, att_src2, att_dst2, as2, ad2, 1, OUTD);
  gat_agg<<<N, OUTD, 0, stream>>>(hmm2, as2, ad2, offs, csr, bias2, out, 1, 6, 0);
}

// Round 14
// 6050.050 us; speedup vs baseline: 1.1736x; 1.0405x over previous
//
#include <hip/hip_runtime.h>
#include <math.h>

#define NN_  10000
#define NE_  320000
#define IND  64
#define HID  128
#define G3   384   // 3*HID
#define HC1  512   // 4 heads * 128
#define OUTD 64

#define CSR_CNT_BLKS 40
#define CSR_FILL_BLKS 40

typedef _Float16 h2f __attribute__((ext_vector_type(2)));
union UH4 { uint4 u; h2f h[4]; };

__device__ __forceinline__ float leakyf_(float x){ return x>0.f ? x : 0.2f*x; }
__device__ __forceinline__ float fsig_(float x){ return 1.f/(1.f+__expf(-x)); }
__device__ __forceinline__ float ftanh_(float x){ float e=__expf(2.f*x); return 1.f-2.f/(e+1.f); }

// LDS-only barrier: waits LDS ops, does NOT drain vmcnt.
#define BARRIER_LDS() asm volatile("s_waitcnt lgkmcnt(0)\n\ts_barrier" ::: "memory")
#define WAIT_VM0()    asm volatile("s_waitcnt vmcnt(0)" ::: "memory")

// agent-scope (device) atomic helpers for cross-block streams
__device__ __forceinline__ float ld_agent(const float* p) {
  return __hip_atomic_load(p, __ATOMIC_RELAXED, __HIP_MEMORY_SCOPE_AGENT);
}
__device__ __forceinline__ void st_agent(float* p, float v) {
  __hip_atomic_store(p, v, __ATOMIC_RELAXED, __HIP_MEMORY_SCOPE_AGENT);
}
__device__ __forceinline__ unsigned ld_agent_u32(const unsigned* p) {
  return __hip_atomic_load(p, __ATOMIC_RELAXED, __HIP_MEMORY_SCOPE_AGENT);
}
__device__ __forceinline__ void st_agent_u32(unsigned* p, unsigned v) {
  __hip_atomic_store(p, v, __ATOMIC_RELAXED, __HIP_MEMORY_SCOPE_AGENT);
}
__device__ __forceinline__ int ld_ctr(const int* p) {
  return __hip_atomic_load(p, __ATOMIC_ACQUIRE, __HIP_MEMORY_SCOPE_AGENT);
}
__device__ __forceinline__ void st_ctr(int* p, int v) {
  __hip_atomic_store(p, v, __ATOMIC_RELEASE, __HIP_MEMORY_SCOPE_AGENT);
}

// ---------------------------------------------------------------------------
// Generic tiled fp32 GEMM.  C[m,n] = sum_k A[m,k] * (TB ? B[n,k] : B[k,n]) + bias[n]
// Optional fused attention-dot epilogue: a_s[m,h] += sum_c C[m, h*Catt+c]*att_src[h,c]
// (valid because each 64-col tile lies within one head: 64 | Catt).
// ---------------------------------------------------------------------------
template<bool TB>
__global__ __launch_bounds__(256) void gemm_k(const float* __restrict__ A,
                                              const float* __restrict__ B,
                                              const float* __restrict__ bias,
                                              float* __restrict__ C,
                                              int M, int N, int K,
                                              const float* __restrict__ att_src,
                                              const float* __restrict__ att_dst,
                                              float* a_s, float* a_d,
                                              int heads, int Catt) {
  __shared__ float As[16][65];
  __shared__ float Bs[16][65];
  __shared__ float sred[64];
  __shared__ float dred[64];
  const int bm = blockIdx.x * 64, bn = blockIdx.y * 64;
  const int tid = threadIdx.x;
  const int tm = (tid >> 4) << 2, tn = (tid & 15) << 2;
  float acc[4][4] = {};
  const int row = tid & 63, kq = (tid >> 6) << 2;
  for (int k0 = 0; k0 < K; k0 += 16) {
    float4 av = make_float4(0.f, 0.f, 0.f, 0.f);
    const int m = bm + row;
    if (m < M) av = *(const float4*)(A + (size_t)m * K + k0 + kq);
    As[kq + 0][row] = av.x; As[kq + 1][row] = av.y;
    As[kq + 2][row] = av.z; As[kq + 3][row] = av.w;
    if (TB) {
      float4 bv = *(const float4*)(B + (size_t)(bn + row) * K + k0 + kq);
      Bs[kq + 0][row] = bv.x; Bs[kq + 1][row] = bv.y;
      Bs[kq + 2][row] = bv.z; Bs[kq + 3][row] = bv.w;
    } else {
      const int kr = tid >> 4, nq = (tid & 15) << 2;
      float4 bv = *(const float4*)(B + (size_t)(k0 + kr) * N + bn + nq);
      Bs[kr][nq + 0] = bv.x; Bs[kr][nq + 1] = bv.y;
      Bs[kr][nq + 2] = bv.z; Bs[kr][nq + 3] = bv.w;
    }
    __syncthreads();
#pragma unroll
    for (int kk = 0; kk < 16; kk++) {
      float a[4], b[4];
#pragma unroll
      for (int i = 0; i < 4; i++) a[i] = As[kk][tm + i];
#pragma unroll
      for (int j = 0; j < 4; j++) b[j] = Bs[kk][tn + j];
#pragma unroll
      for (int i = 0; i < 4; i++)
#pragma unroll
        for (int j = 0; j < 4; j++) acc[i][j] = fmaf(a[i], b[j], acc[i][j]);
    }
    __syncthreads();
  }
#pragma unroll
  for (int i = 0; i < 4; i++) {
    const int m = bm + tm + i;
    if (m < M) {
#pragma unroll
      for (int j = 0; j < 4; j++) {
        const int n = bn + tn + j;
        float v = acc[i][j];
        if (bias) v += bias[n];
        C[(size_t)m * N + n] = v;
      }
    }
  }
  // fused att-dot partial epilogue
  if (att_src) {
    if (tid < 64) { sred[tid] = 0.f; dred[tid] = 0.f; }
    __syncthreads();
    const int h = bn / Catt;                 // head of this col-tile (uniform)
    const int cbase = bn + tn - h * Catt;    // att index of col tn+0
#pragma unroll
    for (int i = 0; i < 4; i++) {
      float ps = 0.f, pd = 0.f;
#pragma unroll
      for (int j = 0; j < 4; j++) {
        const float sa = att_src[h * Catt + cbase + j];
        const float da = att_dst[h * Catt + cbase + j];
        ps = fmaf(acc[i][j], sa, ps);
        pd = fmaf(acc[i][j], da, pd);
      }
      atomicAdd(&sred[tm + i], ps);
      atomicAdd(&dred[tm + i], pd);
    }
    __syncthreads();
    if (tid < 64) {
      const int m = bm + tid;
      if (m < M) {
        atomicAdd(&a_s[m * heads + h], sred[tid]);
        atomicAdd(&a_d[m * heads + h], dred[tid]);
      }
    }
  }
}

// ---------------------------------------------------------------------------
// Pipelined two-layer GRU across 4 CUs (r11 scan core) + CSR build folded in.
//  block 0: layer-0 scan -> fp16 h0 stream + progress ctr every 16 steps
//  blocks 1,2: gi1 factories (parity-split), BATCHED (poll once per 4 items)
//  block 3: layer-1 scan consuming gi1; polls ctrs once per 32 steps
//  blocks 4..: CSR-by-dst build (independent of GRU, overlaps the scan)
// ctr: [0]=prog0 [1]=pf0 [2]=pf1 [3]=count_done [4]=prefix_done [5]=pad
// ---------------------------------------------------------------------------
__global__ __launch_bounds__(256, 1) void gru_pipe(const float* __restrict__ gi0,
                                                   const float* __restrict__ w_hh0,
                                                   const float* __restrict__ b_hh0,
                                                   const float* __restrict__ w_ih1,
                                                   const float* __restrict__ b_ih1,
                                                   const float* __restrict__ w_hh1,
                                                   const float* __restrict__ b_hh1,
                                                   unsigned* h0_st16, float* gi1_st,
                                                   int* ctr,
                                                   float* __restrict__ h1_out,
                                                   int T,
                                                   const int* __restrict__ ei,
                                                   int* cnt, int* offs,
                                                   int* cursor, int* csr, int E) {
  __shared__ _Float16 hbuf[2][HID];
  __shared__ float psum[3][HID];
  __shared__ int sbuf[256];
  __shared__ int scarry;

  const int bid   = blockIdx.x;
  const int tid   = threadIdx.x;

  // ======================= CSR roles (bid >= 4) ==========================
  if (bid >= 4) {
    const int cb = bid - 4;
    if (cb < CSR_CNT_BLKS) {
      for (int e = cb * 256 + tid; e < E; e += CSR_CNT_BLKS * 256)
        atomicAdd(&cnt[ei[E + e]], 1);
      __syncthreads();
      if (tid == 0)
        __hip_atomic_fetch_add(&ctr[3], 1, __ATOMIC_RELEASE, __HIP_MEMORY_SCOPE_AGENT);
    } else if (cb == CSR_CNT_BLKS) {
      if (tid == 0) {
        while (ld_ctr(&ctr[3]) < CSR_CNT_BLKS) __builtin_amdgcn_s_sleep(32);
      }
      __syncthreads();
      if (tid == 0) scarry = 0;
      __syncthreads();
      for (int base = 0; base < NN_; base += 256) {
        const int i = base + tid;
        const int v = (i < NN_) ? cnt[i] : 0;
        sbuf[tid] = v;
        __syncthreads();
        for (int d = 1; d < 256; d <<= 1) {
          int t2 = 0;
          if (tid >= d) t2 = sbuf[tid - d];
          __syncthreads();
          sbuf[tid] += t2;
          __syncthreads();
        }
        const int incl = sbuf[tid] + scarry;
        if (i < NN_) { offs[i] = incl - v; cursor[i] = incl - v; }
        __syncthreads();
        if (tid == 255) scarry = incl;
        __syncthreads();
      }
      if (tid == 0) {
        offs[NN_] = scarry;
        __threadfence();
        st_ctr(&ctr[4], 1);
      }
    } else {
      const int fb = cb - CSR_CNT_BLKS - 1;   // 0..CSR_FILL_BLKS-1
      if (tid == 0) {
        while (ld_ctr(&ctr[4]) < 1) __builtin_amdgcn_s_sleep(64);
      }
      __syncthreads();
      for (int e = fb * 256 + tid; e < E; e += CSR_FILL_BLKS * 256) {
        const int d = ei[E + e];
        const int s = ei[e];
        const int pos = atomicAdd(&cursor[d], 1);
        csr[pos] = s;
      }
    }
    return;
  }

  // ======================= GRU roles (bid 0..3, r11 core) ================
  const int khalf = (tid >> 6) & 1;
  const int j     = (tid & 63) | ((tid >> 7) << 6);
  const int kbase = khalf * 64;

  const float* wsrc = (bid == 0) ? w_hh0 : (bid == 3 ? w_hh1 : w_ih1);
  const float* bsrc = (bid == 0) ? b_hh0 : (bid == 3 ? b_hh1 : b_ih1);

  // load + convert this thread's half-rows of the 3 gates to packed fp16
  h2f wr[32], wz[32], wn[32];
#pragma unroll
  for (int i = 0; i < 16; i++) {
    float4 a = *(const float4*)(wsrc + (size_t)j * HID + kbase + i * 4);
    wr[2 * i]     = h2f{(_Float16)a.x, (_Float16)a.y};
    wr[2 * i + 1] = h2f{(_Float16)a.z, (_Float16)a.w};
  }
#pragma unroll
  for (int i = 0; i < 16; i++) {
    float4 a = *(const float4*)(wsrc + (size_t)(j + HID) * HID + kbase + i * 4);
    wz[2 * i]     = h2f{(_Float16)a.x, (_Float16)a.y};
    wz[2 * i + 1] = h2f{(_Float16)a.z, (_Float16)a.w};
  }
#pragma unroll
  for (int i = 0; i < 16; i++) {
    float4 a = *(const float4*)(wsrc + (size_t)(j + 2 * HID) * HID + kbase + i * 4);
    wn[2 * i]     = h2f{(_Float16)a.x, (_Float16)a.y};
    wn[2 * i + 1] = h2f{(_Float16)a.z, (_Float16)a.w};
  }
  const float b0 = bsrc[j];
  const float b1 = bsrc[j + HID];
  const float b2 = bsrc[j + 2 * HID];

  // dot over this thread's K-half from an LDS fp16 vector at 'hp16'
  auto dot_half = [&](const _Float16* hp16, float& r, float& z, float& n) {
    const uint4* hp = (const uint4*)(hp16 + kbase);
    float ar0 = 0.f, ar1 = 0.f, az0 = 0.f, az1 = 0.f, an0 = 0.f, an1 = 0.f;
#pragma unroll
    for (int c = 0; c < 2; c++) {
      uint4 hv[4];
#pragma unroll
      for (int i = 0; i < 4; i++) hv[i] = hp[c * 4 + i];
#pragma unroll
      for (int i = 0; i < 4; i++) {
        UH4 v; v.u = hv[i];
#pragma unroll
        for (int q = 0; q < 4; q++) {
          const int k = c * 16 + i * 4 + q;
          const h2f hh = v.h[q];
          if (k & 1) {
            ar1 = __builtin_amdgcn_fdot2(wr[k], hh, ar1, false);
            az1 = __builtin_amdgcn_fdot2(wz[k], hh, az1, false);
            an1 = __builtin_amdgcn_fdot2(wn[k], hh, an1, false);
          } else {
            ar0 = __builtin_amdgcn_fdot2(wr[k], hh, ar0, false);
            az0 = __builtin_amdgcn_fdot2(wz[k], hh, az0, false);
            an0 = __builtin_amdgcn_fdot2(wn[k], hh, an0, false);
          }
        }
      }
    }
    r = ar0 + ar1; z = az0 + az1; n = an0 + an1;
  };

  if (bid == 0 || bid == 3) {
    // ---------------- scan roles (bid0 = layer-0, bid3 = layer-1) -----------
    const float* gsrc = (bid == 0) ? gi0 : gi1_st;
    float hcur = 0.f;
    if (khalf == 0) hbuf[0][j] = (_Float16)0.f;
    BARRIER_LDS();

    if (bid == 3 && tid == 0) {            // ensure gi1[0..3] published
      while (ld_ctr(&ctr[1]) < 4) {}
      while (ld_ctr(&ctr[2]) < 4) {}
    }
    if (bid == 3) __syncthreads();

    // four independent prefetch register sets (t mod 4 = 0,1,2,3)
    float gxA, gyA, gzA, gxB, gyB, gzB, gxC, gyC, gzC, gxD, gyD, gzD;
    if (khalf == 0) {
      const float* gp = gsrc + j;
      gxA = gp[0]; gyA = gp[HID]; gzA = gp[2 * HID];
      gp = gsrc + (size_t)1 * G3 + j;
      gxB = gp[0]; gyB = gp[HID]; gzB = gp[2 * HID];
      gp = gsrc + (size_t)2 * G3 + j;
      gxC = gp[0]; gyC = gp[HID]; gzC = gp[2 * HID];
      gp = gsrc + (size_t)3 * G3 + j;
      gxD = gp[0]; gyD = gp[HID]; gzD = gp[2 * HID];
    }

    auto substep = [&](int tc, int pin, float& gx, float& gy, float& gz) {
      float dr, dz, dn;
      dot_half(&hbuf[pin][0], dr, dz, dn);
      if (khalf == 1) { psum[0][j] = dr; psum[1][j] = dz; psum[2][j] = dn; }
      BARRIER_LDS();
      if (khalf == 0) {
        const float r = fsig_(gx + b0 + dr + psum[0][j]);
        const float z = fsig_(gy + b1 + dz + psum[1][j]);
        const float n = ftanh_(gz + r * (b2 + dn + psum[2][j]));
        hcur = (1.f - z) * n + z * hcur;
        hbuf[pin ^ 1][j] = (_Float16)hcur;
        if (bid == 3) h1_out[(size_t)tc * HID + j] = hcur;
        // reload this set for tc+4 (consumed 4 sub-steps later)
        const int tp = (tc + 4 < T) ? (tc + 4) : 0;
        const float* gp = gsrc + (size_t)tp * G3 + j;
        gx = gp[0]; gy = gp[HID]; gz = gp[2 * HID];
      }
      // consumer: poll once per 32 steps, deep margin (amortized LLC spin)
      if (bid == 3 && tid == 0 && (tc & 31) == 0) {
        int need = tc + 36; if (need > T) need = T;
        while (ld_ctr(&ctr[1]) < need) {}
        while (ld_ctr(&ctr[2]) < need) {}
      }
      BARRIER_LDS();
      // producer: wave 1 (stores only in its vmcnt) exports fp16 h0[tc]
      if (bid == 0 && tid >= 64 && tid < 128) {
        const int idx = tid - 64;
        unsigned v = *(const unsigned*)&hbuf[pin ^ 1][2 * idx];
        st_agent_u32(&h0_st16[(size_t)tc * 64 + idx], v);
        if ((tc & 15) == 15) {
          WAIT_VM0();                        // drains only wave-1 stores
          if (tid == 64) st_ctr(&ctr[0], tc + 1);
        }
      }
    };

    for (int t = 0; t < T; t += 4) {
      substep(t,     0, gxA, gyA, gzA);
      substep(t + 1, 1, gxB, gyB, gzB);
      substep(t + 2, 0, gxC, gyC, gzC);
      substep(t + 3, 1, gxD, gyD, gzD);
    }
    if (bid == 0 && tid >= 64 && tid < 128) {  // final publish
      WAIT_VM0();
      if (tid == 64) st_ctr(&ctr[0], T);
    }
  } else {
    // ---------------- factory roles (gi1 for parity f), BATCHED -------------
    const int f = bid - 1;                    // 0 or 1
    _Float16* hstage = &hbuf[0][0];           // single staging buffer
    for (int t0 = f; t0 < T; t0 += 8) {       // batch: t0, t0+2, t0+4, t0+6
      if (tid == 0) {
        int need = t0 + 7; if (need > T) need = T;
        while (ld_ctr(&ctr[0]) < need) {}
      }
      __syncthreads();
      // prefetch all 4 h0 vectors for this batch into registers
      unsigned hv0 = 0, hv1 = 0, hv2 = 0, hv3 = 0;
      if (tid < 64) {
        hv0 = ld_agent_u32(&h0_st16[(size_t)t0 * 64 + tid]);
        if (t0 + 2 < T) hv1 = ld_agent_u32(&h0_st16[(size_t)(t0 + 2) * 64 + tid]);
        if (t0 + 4 < T) hv2 = ld_agent_u32(&h0_st16[(size_t)(t0 + 4) * 64 + tid]);
        if (t0 + 6 < T) hv3 = ld_agent_u32(&h0_st16[(size_t)(t0 + 6) * 64 + tid]);
      }
#pragma unroll
      for (int k = 0; k < 4; k++) {
        const int t = t0 + 2 * k;
        if (t >= T) break;
        if (tid < 64) {
          const unsigned hv = (k == 0) ? hv0 : (k == 1) ? hv1 : (k == 2) ? hv2 : hv3;
          ((unsigned*)hstage)[tid] = hv;
        }
        BARRIER_LDS();
        float dr, dz, dn;
        dot_half(hstage, dr, dz, dn);
        if (khalf == 1) { psum[0][j] = dr; psum[1][j] = dz; psum[2][j] = dn; }
        BARRIER_LDS();
        if (khalf == 0) {
          float* gp = gi1_st + (size_t)t * G3 + j;
          st_agent(gp,           dr + psum[0][j] + b0);
          st_agent(gp + HID,     dz + psum[1][j] + b1);
          st_agent(gp + 2 * HID, dn + psum[2][j] + b2);
        }
      }
      __syncthreads();                        // drain gi1 stores (all waves)
      if (tid == 0) {
        int pub = t0 + 8; if (pub > T) pub = T;
        st_ctr(&ctr[1 + f], pub);
      }
    }
    __syncthreads();
    if (tid == 0) st_ctr(&ctr[1 + f], T);
  }
}

// ---------------------------------------------------------------------------
// GAT softmax-aggregation.  One block per dst node; blockDim = heads<<cshift.
// ---------------------------------------------------------------------------
__global__ void gat_agg(const float* __restrict__ feat,
                        const float* __restrict__ a_s, const float* __restrict__ a_d,
                        const int* __restrict__ offs, const int* __restrict__ csr,
                        const float* __restrict__ bias, float* __restrict__ out,
                        int heads, int cshift, int do_relu) {
  const int n = blockIdx.x;
  const int t = threadIdx.x;
  const int HC = blockDim.x;
  const int h = t >> cshift;
  const int beg = offs[n], end = offs[n + 1];
  const float ad = a_d[n * heads + h];
  const float self_e = leakyf_(a_s[n * heads + h] + ad);
  float m = self_e;
  for (int i = beg; i < end; i++) {
    const int s = csr[i];
    m = fmaxf(m, leakyf_(a_s[s * heads + h] + ad));
  }
  float den = expf(self_e - m);
  float acc = den * feat[(size_t)n * HC + t];
  for (int i = beg; i < end; i++) {
    const int s = csr[i];
    const float wgt = expf(leakyf_(a_s[s * heads + h] + ad) - m);
    den += wgt;
    acc = fmaf(wgt, feat[(size_t)s * HC + t], acc);
  }
  float o = acc / den + bias[t];
  if (do_relu) o = fmaxf(o, 0.f);
  out[(size_t)n * HC + t] = o;
}

// ---------------------------------------------------------------------------
extern "C" void kernel_launch(void* const* d_in, const int* in_sizes, int n_in,
                              void* d_out, int out_size, void* d_ws, size_t ws_size,
                              hipStream_t stream) {
  const float* x        = (const float*)d_in[0];
  const int*   ei       = (const int*)d_in[1];   // int64 inputs arrive as int32
  const float* w_ih0    = (const float*)d_in[2];
  const float* w_hh0    = (const float*)d_in[3];
  const float* b_ih0    = (const float*)d_in[4];
  const float* b_hh0    = (const float*)d_in[5];
  const float* w_ih1    = (const float*)d_in[6];
  const float* w_hh1    = (const float*)d_in[7];
  const float* b_ih1    = (const float*)d_in[8];
  const float* b_hh1    = (const float*)d_in[9];
  const float* W1       = (const float*)d_in[10];
  const float* att_src1 = (const float*)d_in[11];
  const float* att_dst1 = (const float*)d_in[12];
  const float* bias1    = (const float*)d_in[13];
  const float* W2       = (const float*)d_in[14];
  const float* att_src2 = (const float*)d_in[15];
  const float* att_dst2 = (const float*)d_in[16];
  const float* bias2    = (const float*)d_in[17];
  float* out = (float*)d_out;

  const int N = NN_;
  const int E = in_sizes[1] / 2;

  // ---- workspace layout with overlays (peak ~54 MB) ----
  float* f    = (float*)d_ws;
  float* gi   = f;                         // region A (gi0; dead after scan)
  float* hmm1 = f;                         // = A, reused for GAT1 features
  float* h1   = f + (size_t)N * HC1;                    // B
  float* g1o  = h1 + (size_t)N * HID;                   // C (post-scan)
  float* hmm2 = g1o + (size_t)N * HC1;                  // D
  float* as1  = hmm2 + (size_t)N * OUTD;
  float* ad1  = as1 + (size_t)N * 4;
  float* as2  = ad1 + (size_t)N * 4;
  float* ad2  = as2 + (size_t)N;
  int* cnt    = (int*)(ad2 + (size_t)N);
  int* offs   = cnt + N;        // N+1
  int* cursor = offs + (N + 1);
  int* csr    = cursor + N;     // E
  int* ctr    = csr + E;        // 6 ints
  // scan-time streams overlay region C (g1o): N*64 uints (fp16 h0) + N*G3
  // floats (gi1) = N*448 float-slots <= N*HC1 ✓
  unsigned* h0_st16 = (unsigned*)g1o;
  float*    gi1_st  = g1o + (size_t)N * 64;

  const int mblocks = (N + 63) / 64;

  // GRU: gi0 GEMM, zero counters+cnt+att-dot accumulators, then fused
  // pipelined scan + CSR build
  gemm_k<true><<<dim3(mblocks, G3 / 64), 256, 0, stream>>>(
      x, w_ih0, b_ih0, gi, N, G3, IND, nullptr, nullptr, nullptr, nullptr, 0, 0);
  hipMemsetAsync(ctr, 0, 6 * sizeof(int), stream);
  hipMemsetAsync(cnt, 0, (size_t)N * sizeof(int), stream);
  hipMemsetAsync(as1, 0, (size_t)N * 10 * sizeof(float), stream);  // as1,ad1,as2,ad2
  gru_pipe<<<4 + CSR_CNT_BLKS + 1 + CSR_FILL_BLKS, 256, 0, stream>>>(
      gi, w_hh0, b_hh0, w_ih1, b_ih1, w_hh1, b_hh1,
      h0_st16, gi1_st, ctr, h1, N, ei, cnt, offs, cursor, csr, E);

  // GAT layer 1 (att dots fused into GEMM epilogue)
  gemm_k<false><<<dim3(mblocks, HC1 / 64), 256, 0, stream>>>(
      h1, W1, nullptr, hmm1, N, HC1, HID, att_src1, att_dst1, as1, ad1, 4, HID);
  gat_agg<<<N, HC1, 0, stream>>>(hmm1, as1, ad1, offs, csr, bias1, g1o, 4, 7, 1);

  // GAT layer 2 (att dots fused into GEMM epilogue)
  gemm_k<false><<<dim3(mblocks, OUTD / 64), 256, 0, stream>>>(
      g1o, W2, nullptr, hmm2, N, OUTD, HC1, att_src2, att_dst2, as2, ad2, 1, OUTD);
  gat_agg<<<N, OUTD, 0, stream>>>(hmm2, as2, ad2, offs, csr, bias2, out, 1, 6, 0);
}

// Round 15
// 5901.492 us; speedup vs baseline: 1.2032x; 1.0252x over previous
//
#include <hip/hip_runtime.h>
#include <math.h>

#define NN_  10000
#define NE_  320000
#define IND  64
#define HID  128
#define G3   384   // 3*HID
#define HC1  512   // 4 heads * 128
#define OUTD 64

#define CSR_CNT_BLKS 40
#define CSR_FILL_BLKS 40

typedef _Float16 h2f __attribute__((ext_vector_type(2)));
union UH4 { uint4 u; h2f h[4]; };

__device__ __forceinline__ float leakyf_(float x){ return x>0.f ? x : 0.2f*x; }
__device__ __forceinline__ float fsig_(float x){ return 1.f/(1.f+__expf(-x)); }
__device__ __forceinline__ float ftanh_(float x){ float e=__expf(2.f*x); return 1.f-2.f/(e+1.f); }

// LDS-only barrier: waits LDS ops, does NOT drain vmcnt.
#define BARRIER_LDS() asm volatile("s_waitcnt lgkmcnt(0)\n\ts_barrier" ::: "memory")
#define WAIT_VM0()    asm volatile("s_waitcnt vmcnt(0)" ::: "memory")

// agent-scope (device) atomic helpers for cross-block streams
__device__ __forceinline__ float ld_agent(const float* p) {
  return __hip_atomic_load(p, __ATOMIC_RELAXED, __HIP_MEMORY_SCOPE_AGENT);
}
__device__ __forceinline__ void st_agent(float* p, float v) {
  __hip_atomic_store(p, v, __ATOMIC_RELAXED, __HIP_MEMORY_SCOPE_AGENT);
}
__device__ __forceinline__ unsigned ld_agent_u32(const unsigned* p) {
  return __hip_atomic_load(p, __ATOMIC_RELAXED, __HIP_MEMORY_SCOPE_AGENT);
}
__device__ __forceinline__ void st_agent_u32(unsigned* p, unsigned v) {
  __hip_atomic_store(p, v, __ATOMIC_RELAXED, __HIP_MEMORY_SCOPE_AGENT);
}
__device__ __forceinline__ int ld_ctr(const int* p) {
  return __hip_atomic_load(p, __ATOMIC_ACQUIRE, __HIP_MEMORY_SCOPE_AGENT);
}
__device__ __forceinline__ void st_ctr(int* p, int v) {
  __hip_atomic_store(p, v, __ATOMIC_RELEASE, __HIP_MEMORY_SCOPE_AGENT);
}

// ---------------------------------------------------------------------------
// Generic tiled fp32 GEMM.  C[m,n] = sum_k A[m,k] * (TB ? B[n,k] : B[k,n]) + bias[n]
// Optional fused attention-dot epilogue: a_s[m,h] += sum_c C[m, h*Catt+c]*att_src[h,c]
// ---------------------------------------------------------------------------
template<bool TB>
__global__ __launch_bounds__(256) void gemm_k(const float* __restrict__ A,
                                              const float* __restrict__ B,
                                              const float* __restrict__ bias,
                                              float* __restrict__ C,
                                              int M, int N, int K,
                                              const float* __restrict__ att_src,
                                              const float* __restrict__ att_dst,
                                              float* a_s, float* a_d,
                                              int heads, int Catt) {
  __shared__ float As[16][65];
  __shared__ float Bs[16][65];
  __shared__ float sred[64];
  __shared__ float dred[64];
  const int bm = blockIdx.x * 64, bn = blockIdx.y * 64;
  const int tid = threadIdx.x;
  const int tm = (tid >> 4) << 2, tn = (tid & 15) << 2;
  float acc[4][4] = {};
  const int row = tid & 63, kq = (tid >> 6) << 2;
  for (int k0 = 0; k0 < K; k0 += 16) {
    float4 av = make_float4(0.f, 0.f, 0.f, 0.f);
    const int m = bm + row;
    if (m < M) av = *(const float4*)(A + (size_t)m * K + k0 + kq);
    As[kq + 0][row] = av.x; As[kq + 1][row] = av.y;
    As[kq + 2][row] = av.z; As[kq + 3][row] = av.w;
    if (TB) {
      float4 bv = *(const float4*)(B + (size_t)(bn + row) * K + k0 + kq);
      Bs[kq + 0][row] = bv.x; Bs[kq + 1][row] = bv.y;
      Bs[kq + 2][row] = bv.z; Bs[kq + 3][row] = bv.w;
    } else {
      const int kr = tid >> 4, nq = (tid & 15) << 2;
      float4 bv = *(const float4*)(B + (size_t)(k0 + kr) * N + bn + nq);
      Bs[kr][nq + 0] = bv.x; Bs[kr][nq + 1] = bv.y;
      Bs[kr][nq + 2] = bv.z; Bs[kr][nq + 3] = bv.w;
    }
    __syncthreads();
#pragma unroll
    for (int kk = 0; kk < 16; kk++) {
      float a[4], b[4];
#pragma unroll
      for (int i = 0; i < 4; i++) a[i] = As[kk][tm + i];
#pragma unroll
      for (int j = 0; j < 4; j++) b[j] = Bs[kk][tn + j];
#pragma unroll
      for (int i = 0; i < 4; i++)
#pragma unroll
        for (int j = 0; j < 4; j++) acc[i][j] = fmaf(a[i], b[j], acc[i][j]);
    }
    __syncthreads();
  }
#pragma unroll
  for (int i = 0; i < 4; i++) {
    const int m = bm + tm + i;
    if (m < M) {
#pragma unroll
      for (int j = 0; j < 4; j++) {
        const int n = bn + tn + j;
        float v = acc[i][j];
        if (bias) v += bias[n];
        C[(size_t)m * N + n] = v;
      }
    }
  }
  // fused att-dot partial epilogue
  if (att_src) {
    if (tid < 64) { sred[tid] = 0.f; dred[tid] = 0.f; }
    __syncthreads();
    const int h = bn / Catt;                 // head of this col-tile (uniform)
    const int cbase = bn + tn - h * Catt;    // att index of col tn+0
#pragma unroll
    for (int i = 0; i < 4; i++) {
      float ps = 0.f, pd = 0.f;
#pragma unroll
      for (int j = 0; j < 4; j++) {
        const float sa = att_src[h * Catt + cbase + j];
        const float da = att_dst[h * Catt + cbase + j];
        ps = fmaf(acc[i][j], sa, ps);
        pd = fmaf(acc[i][j], da, pd);
      }
      atomicAdd(&sred[tm + i], ps);
      atomicAdd(&dred[tm + i], pd);
    }
    __syncthreads();
    if (tid < 64) {
      const int m = bm + tid;
      if (m < M) {
        atomicAdd(&a_s[m * heads + h], sred[tid]);
        atomicAdd(&a_d[m * heads + h], dred[tid]);
      }
    }
  }
}

// ---------------------------------------------------------------------------
// Pipelined two-layer GRU across 4 CUs (r11 scan core) + CSR build folded in.
//  block 0: layer-0 scan -> fp16 h0 stream + progress ctr every 16 steps
//  blocks 1,2: gi1 factories (parity-split), BATCHED (poll once per 4 items)
//  block 3: layer-1 scan consuming gi1; polls ctrs once per 32 steps
//  blocks 4..: CSR-by-dst build (independent of GRU, overlaps the scan)
// ctr: [0]=prog0 [1]=pf0 [2]=pf1 [3]=count_done [4]=prefix_done [5]=pad
// ---------------------------------------------------------------------------
__global__ __launch_bounds__(256, 1) void gru_pipe(const float* __restrict__ gi0,
                                                   const float* __restrict__ w_hh0,
                                                   const float* __restrict__ b_hh0,
                                                   const float* __restrict__ w_ih1,
                                                   const float* __restrict__ b_ih1,
                                                   const float* __restrict__ w_hh1,
                                                   const float* __restrict__ b_hh1,
                                                   unsigned* h0_st16, float* gi1_st,
                                                   int* ctr,
                                                   float* __restrict__ h1_out,
                                                   int T,
                                                   const int* __restrict__ ei,
                                                   int* cnt, int* offs,
                                                   int* cursor, int* csr, int E) {
  __shared__ _Float16 hbuf[2][HID];
  __shared__ float psum[3][HID];
  __shared__ int sbuf[256];
  __shared__ int scarry;

  const int bid   = blockIdx.x;
  const int tid   = threadIdx.x;

  // ======================= CSR roles (bid >= 4) ==========================
  if (bid >= 4) {
    const int cb = bid - 4;
    if (cb < CSR_CNT_BLKS) {
      for (int e = cb * 256 + tid; e < E; e += CSR_CNT_BLKS * 256)
        atomicAdd(&cnt[ei[E + e]], 1);
      __syncthreads();
      if (tid == 0)
        __hip_atomic_fetch_add(&ctr[3], 1, __ATOMIC_RELEASE, __HIP_MEMORY_SCOPE_AGENT);
    } else if (cb == CSR_CNT_BLKS) {
      if (tid == 0) {
        while (ld_ctr(&ctr[3]) < CSR_CNT_BLKS) __builtin_amdgcn_s_sleep(32);
      }
      __syncthreads();
      if (tid == 0) scarry = 0;
      __syncthreads();
      for (int base = 0; base < NN_; base += 256) {
        const int i = base + tid;
        const int v = (i < NN_) ? cnt[i] : 0;
        sbuf[tid] = v;
        __syncthreads();
        for (int d = 1; d < 256; d <<= 1) {
          int t2 = 0;
          if (tid >= d) t2 = sbuf[tid - d];
          __syncthreads();
          sbuf[tid] += t2;
          __syncthreads();
        }
        const int incl = sbuf[tid] + scarry;
        if (i < NN_) { offs[i] = incl - v; cursor[i] = incl - v; }
        __syncthreads();
        if (tid == 255) scarry = incl;
        __syncthreads();
      }
      if (tid == 0) {
        offs[NN_] = scarry;
        __threadfence();
        st_ctr(&ctr[4], 1);
      }
    } else {
      const int fb = cb - CSR_CNT_BLKS - 1;   // 0..CSR_FILL_BLKS-1
      if (tid == 0) {
        while (ld_ctr(&ctr[4]) < 1) __builtin_amdgcn_s_sleep(64);
      }
      __syncthreads();
      for (int e = fb * 256 + tid; e < E; e += CSR_FILL_BLKS * 256) {
        const int d = ei[E + e];
        const int s = ei[e];
        const int pos = atomicAdd(&cursor[d], 1);
        csr[pos] = s;
      }
    }
    return;
  }

  // ======================= GRU roles (bid 0..3, r11 core) ================
  const int khalf = (tid >> 6) & 1;
  const int j     = (tid & 63) | ((tid >> 7) << 6);
  const int kbase = khalf * 64;

  const float* wsrc = (bid == 0) ? w_hh0 : (bid == 3 ? w_hh1 : w_ih1);
  const float* bsrc = (bid == 0) ? b_hh0 : (bid == 3 ? b_hh1 : b_ih1);

  // load + convert this thread's half-rows of the 3 gates to packed fp16
  h2f wr[32], wz[32], wn[32];
#pragma unroll
  for (int i = 0; i < 16; i++) {
    float4 a = *(const float4*)(wsrc + (size_t)j * HID + kbase + i * 4);
    wr[2 * i]     = h2f{(_Float16)a.x, (_Float16)a.y};
    wr[2 * i + 1] = h2f{(_Float16)a.z, (_Float16)a.w};
  }
#pragma unroll
  for (int i = 0; i < 16; i++) {
    float4 a = *(const float4*)(wsrc + (size_t)(j + HID) * HID + kbase + i * 4);
    wz[2 * i]     = h2f{(_Float16)a.x, (_Float16)a.y};
    wz[2 * i + 1] = h2f{(_Float16)a.z, (_Float16)a.w};
  }
#pragma unroll
  for (int i = 0; i < 16; i++) {
    float4 a = *(const float4*)(wsrc + (size_t)(j + 2 * HID) * HID + kbase + i * 4);
    wn[2 * i]     = h2f{(_Float16)a.x, (_Float16)a.y};
    wn[2 * i + 1] = h2f{(_Float16)a.z, (_Float16)a.w};
  }
  const float b0 = bsrc[j];
  const float b1 = bsrc[j + HID];
  const float b2 = bsrc[j + 2 * HID];

  // dot over this thread's K-half from an LDS fp16 vector at 'hp16'
  auto dot_half = [&](const _Float16* hp16, float& r, float& z, float& n) {
    const uint4* hp = (const uint4*)(hp16 + kbase);
    float ar0 = 0.f, ar1 = 0.f, az0 = 0.f, az1 = 0.f, an0 = 0.f, an1 = 0.f;
#pragma unroll
    for (int c = 0; c < 2; c++) {
      uint4 hv[4];
#pragma unroll
      for (int i = 0; i < 4; i++) hv[i] = hp[c * 4 + i];
#pragma unroll
      for (int i = 0; i < 4; i++) {
        UH4 v; v.u = hv[i];
#pragma unroll
        for (int q = 0; q < 4; q++) {
          const int k = c * 16 + i * 4 + q;
          const h2f hh = v.h[q];
          if (k & 1) {
            ar1 = __builtin_amdgcn_fdot2(wr[k], hh, ar1, false);
            az1 = __builtin_amdgcn_fdot2(wz[k], hh, az1, false);
            an1 = __builtin_amdgcn_fdot2(wn[k], hh, an1, false);
          } else {
            ar0 = __builtin_amdgcn_fdot2(wr[k], hh, ar0, false);
            az0 = __builtin_amdgcn_fdot2(wz[k], hh, az0, false);
            an0 = __builtin_amdgcn_fdot2(wn[k], hh, an0, false);
          }
        }
      }
    }
    r = ar0 + ar1; z = az0 + az1; n = an0 + an1;
  };

  if (bid == 0 || bid == 3) {
    // ---------------- scan roles (bid0 = layer-0, bid3 = layer-1) -----------
    const float* gsrc = (bid == 0) ? gi0 : gi1_st;
    float hcur = 0.f;
    if (khalf == 0) hbuf[0][j] = (_Float16)0.f;
    BARRIER_LDS();

    if (bid == 3 && tid == 0) {            // ensure gi1[0..3] published
      while (ld_ctr(&ctr[1]) < 4) {}
      while (ld_ctr(&ctr[2]) < 4) {}
    }
    if (bid == 3) __syncthreads();

    // four independent prefetch register sets (t mod 4 = 0,1,2,3)
    float gxA, gyA, gzA, gxB, gyB, gzB, gxC, gyC, gzC, gxD, gyD, gzD;
    if (khalf == 0) {
      const float* gp = gsrc + j;
      gxA = gp[0]; gyA = gp[HID]; gzA = gp[2 * HID];
      gp = gsrc + (size_t)1 * G3 + j;
      gxB = gp[0]; gyB = gp[HID]; gzB = gp[2 * HID];
      gp = gsrc + (size_t)2 * G3 + j;
      gxC = gp[0]; gyC = gp[HID]; gzC = gp[2 * HID];
      gp = gsrc + (size_t)3 * G3 + j;
      gxD = gp[0]; gyD = gp[HID]; gzD = gp[2 * HID];
    }

    auto substep = [&](int tc, int pin, float& gx, float& gy, float& gz) {
      float dr, dz, dn;
      dot_half(&hbuf[pin][0], dr, dz, dn);
      if (khalf == 1) { psum[0][j] = dr; psum[1][j] = dz; psum[2][j] = dn; }
      BARRIER_LDS();
      if (khalf == 0) {
        const float r = fsig_(gx + b0 + dr + psum[0][j]);
        const float z = fsig_(gy + b1 + dz + psum[1][j]);
        const float n = ftanh_(gz + r * (b2 + dn + psum[2][j]));
        hcur = (1.f - z) * n + z * hcur;
        hbuf[pin ^ 1][j] = (_Float16)hcur;
        if (bid == 3) h1_out[(size_t)tc * HID + j] = hcur;
        // reload this set for tc+4 (consumed 4 sub-steps later)
        const int tp = (tc + 4 < T) ? (tc + 4) : 0;
        const float* gp = gsrc + (size_t)tp * G3 + j;
        gx = gp[0]; gy = gp[HID]; gz = gp[2 * HID];
      }
      // consumer: poll once per 32 steps, deep margin (amortized LLC spin)
      if (bid == 3 && tid == 0 && (tc & 31) == 0) {
        int need = tc + 36; if (need > T) need = T;
        while (ld_ctr(&ctr[1]) < need) {}
        while (ld_ctr(&ctr[2]) < need) {}
      }
      BARRIER_LDS();
      // producer: wave 1 (stores only in its vmcnt) exports fp16 h0[tc]
      if (bid == 0 && tid >= 64 && tid < 128) {
        const int idx = tid - 64;
        unsigned v = *(const unsigned*)&hbuf[pin ^ 1][2 * idx];
        st_agent_u32(&h0_st16[(size_t)tc * 64 + idx], v);
        if ((tc & 15) == 15) {
          WAIT_VM0();                        // drains only wave-1 stores
          if (tid == 64) st_ctr(&ctr[0], tc + 1);
        }
      }
    };

    for (int t = 0; t < T; t += 4) {
      substep(t,     0, gxA, gyA, gzA);
      substep(t + 1, 1, gxB, gyB, gzB);
      substep(t + 2, 0, gxC, gyC, gzC);
      substep(t + 3, 1, gxD, gyD, gzD);
    }
    if (bid == 0 && tid >= 64 && tid < 128) {  // final publish
      WAIT_VM0();
      if (tid == 64) st_ctr(&ctr[0], T);
    }
  } else {
    // ---------------- factory roles (gi1 for parity f), BATCHED -------------
    const int f = bid - 1;                    // 0 or 1
    _Float16* hstage = &hbuf[0][0];           // single staging buffer
    for (int t0 = f; t0 < T; t0 += 8) {       // batch: t0, t0+2, t0+4, t0+6
      if (tid == 0) {
        int need = t0 + 7; if (need > T) need = T;
        while (ld_ctr(&ctr[0]) < need) {}
      }
      __syncthreads();
      // prefetch all 4 h0 vectors for this batch into registers
      unsigned hv0 = 0, hv1 = 0, hv2 = 0, hv3 = 0;
      if (tid < 64) {
        hv0 = ld_agent_u32(&h0_st16[(size_t)t0 * 64 + tid]);
        if (t0 + 2 < T) hv1 = ld_agent_u32(&h0_st16[(size_t)(t0 + 2) * 64 + tid]);
        if (t0 + 4 < T) hv2 = ld_agent_u32(&h0_st16[(size_t)(t0 + 4) * 64 + tid]);
        if (t0 + 6 < T) hv3 = ld_agent_u32(&h0_st16[(size_t)(t0 + 6) * 64 + tid]);
      }
#pragma unroll
      for (int k = 0; k < 4; k++) {
        const int t = t0 + 2 * k;
        if (t >= T) break;
        if (tid < 64) {
          const unsigned hv = (k == 0) ? hv0 : (k == 1) ? hv1 : (k == 2) ? hv2 : hv3;
          ((unsigned*)hstage)[tid] = hv;
        }
        BARRIER_LDS();
        float dr, dz, dn;
        dot_half(hstage, dr, dz, dn);
        if (khalf == 1) { psum[0][j] = dr; psum[1][j] = dz; psum[2][j] = dn; }
        BARRIER_LDS();
        if (khalf == 0) {
          float* gp = gi1_st + (size_t)t * G3 + j;
          st_agent(gp,           dr + psum[0][j] + b0);
          st_agent(gp + HID,     dz + psum[1][j] + b1);
          st_agent(gp + 2 * HID, dn + psum[2][j] + b2);
        }
      }
      __syncthreads();                        // drain gi1 stores (all waves)
      if (tid == 0) {
        int pub = t0 + 8; if (pub > T) pub = T;
        st_ctr(&ctr[1 + f], pub);
      }
    }
    __syncthreads();
    if (tid == 0) st_ctr(&ctr[1 + f], T);
  }
}

// ---------------------------------------------------------------------------
// GAT softmax-aggregation, chunked online-softmax with PARALLEL alpha.
// One block per dst node; blockDim = heads<<cshift.  Per chunk of C edges:
// each thread (c,h) gathers a_s for ONE edge in parallel (kills the old
// serialized per-edge a_s latency chains), e staged in LDS [h*C+c]
// (stride-1, conflict-free), chunk max via LDS broadcast scan (same order
// per head -> consistent), online rescale of (m,den,acc), alphas computed
// once per (edge,head).  Gather loop: LDS alpha + staged csr + feat fma.
// Self-loop initializes m/den/acc (matches reference segment max/sum).
// ---------------------------------------------------------------------------
__global__ void gat_agg(const float* __restrict__ feat,
                        const float* __restrict__ a_s, const float* __restrict__ a_d,
                        const int* __restrict__ offs, const int* __restrict__ csr,
                        const float* __restrict__ bias, float* __restrict__ out,
                        int heads, int cshift, int do_relu) {
  __shared__ float ech[512];   // e / alpha per (head, edge-in-chunk)
  __shared__ int scs[128];     // staged csr for the chunk
  const int n = blockIdx.x;
  const int t = threadIdx.x;
  const int HC = blockDim.x;
  const int h = t >> cshift;
  const int C = 1 << cshift;
  const int c = t & (C - 1);
  const int beg = offs[n], end = offs[n + 1];
  const float ad = a_d[n * heads + h];
  float m = leakyf_(a_s[n * heads + h] + ad);   // self edge
  float den = 1.f;
  float acc = feat[(size_t)n * HC + t];
  for (int base = beg; base < end; base += C) {
    const int cnt = min(C, end - base);
    // phase 1: parallel e compute + csr stage
    float ev = 0.f;
    if (c < cnt) {
      const int sv = csr[base + c];
      if (h == 0) scs[c] = sv;
      ev = leakyf_(a_s[sv * heads + h] + ad);
      ech[h * C + c] = ev;
    }
    __syncthreads();
    // phase 2: chunk max (broadcast LDS scan; identical per head)
    float mc = m;
    for (int i = 0; i < cnt; i++) mc = fmaxf(mc, ech[h * C + i]);
    if (mc > m) {
      const float sc = __expf(m - mc);
      den *= sc; acc *= sc; m = mc;
    }
    __syncthreads();
    // phase 3: alpha once per (edge,head)
    if (c < cnt) ech[h * C + c] = __expf(ev - mc);
    __syncthreads();
    // phase 4: accumulate (feat gather is the bandwidth floor)
    for (int i = 0; i < cnt; i++) {
      const float al = ech[h * C + i];
      const int s = scs[i];
      den += al;
      acc = fmaf(al, feat[(size_t)s * HC + t], acc);
    }
    __syncthreads();
  }
  float o = acc / den + bias[t];
  if (do_relu) o = fmaxf(o, 0.f);
  out[(size_t)n * HC + t] = o;
}

// ---------------------------------------------------------------------------
extern "C" void kernel_launch(void* const* d_in, const int* in_sizes, int n_in,
                              void* d_out, int out_size, void* d_ws, size_t ws_size,
                              hipStream_t stream) {
  const float* x        = (const float*)d_in[0];
  const int*   ei       = (const int*)d_in[1];   // int64 inputs arrive as int32
  const float* w_ih0    = (const float*)d_in[2];
  const float* w_hh0    = (const float*)d_in[3];
  const float* b_ih0    = (const float*)d_in[4];
  const float* b_hh0    = (const float*)d_in[5];
  const float* w_ih1    = (const float*)d_in[6];
  const float* w_hh1    = (const float*)d_in[7];
  const float* b_ih1    = (const float*)d_in[8];
  const float* b_hh1    = (const float*)d_in[9];
  const float* W1       = (const float*)d_in[10];
  const float* att_src1 = (const float*)d_in[11];
  const float* att_dst1 = (const float*)d_in[12];
  const float* bias1    = (const float*)d_in[13];
  const float* W2       = (const float*)d_in[14];
  const float* att_src2 = (const float*)d_in[15];
  const float* att_dst2 = (const float*)d_in[16];
  const float* bias2    = (const float*)d_in[17];
  float* out = (float*)d_out;

  const int N = NN_;
  const int E = in_sizes[1] / 2;

  // ---- workspace layout with overlays (peak ~54 MB) ----
  float* f    = (float*)d_ws;
  float* gi   = f;                         // region A (gi0; dead after scan)
  float* hmm1 = f;                         // = A, reused for GAT1 features
  float* h1   = f + (size_t)N * HC1;                    // B
  float* g1o  = h1 + (size_t)N * HID;                   // C (post-scan)
  float* hmm2 = g1o + (size_t)N * HC1;                  // D
  float* as1  = hmm2 + (size_t)N * OUTD;
  float* ad1  = as1 + (size_t)N * 4;
  float* as2  = ad1 + (size_t)N * 4;
  float* ad2  = as2 + (size_t)N;
  int* cnt    = (int*)(ad2 + (size_t)N);
  int* offs   = cnt + N;        // N+1
  int* cursor = offs + (N + 1);
  int* csr    = cursor + N;     // E
  int* ctr    = csr + E;        // 6 ints
  // scan-time streams overlay region C (g1o): N*64 uints (fp16 h0) + N*G3
  // floats (gi1) = N*448 float-slots <= N*HC1 ✓
  unsigned* h0_st16 = (unsigned*)g1o;
  float*    gi1_st  = g1o + (size_t)N * 64;

  const int mblocks = (N + 63) / 64;

  // GRU: gi0 GEMM, zero counters+cnt+att-dot accumulators, then fused
  // pipelined scan + CSR build
  gemm_k<true><<<dim3(mblocks, G3 / 64), 256, 0, stream>>>(
      x, w_ih0, b_ih0, gi, N, G3, IND, nullptr, nullptr, nullptr, nullptr, 0, 0);
  hipMemsetAsync(ctr, 0, 6 * sizeof(int), stream);
  hipMemsetAsync(cnt, 0, (size_t)N * sizeof(int), stream);
  hipMemsetAsync(as1, 0, (size_t)N * 10 * sizeof(float), stream);  // as1,ad1,as2,ad2
  gru_pipe<<<4 + CSR_CNT_BLKS + 1 + CSR_FILL_BLKS, 256, 0, stream>>>(
      gi, w_hh0, b_hh0, w_ih1, b_ih1, w_hh1, b_hh1,
      h0_st16, gi1_st, ctr, h1, N, ei, cnt, offs, cursor, csr, E);

  // GAT layer 1 (att dots fused into GEMM epilogue)
  gemm_k<false><<<dim3(mblocks, HC1 / 64), 256, 0, stream>>>(
      h1, W1, nullptr, hmm1, N, HC1, HID, att_src1, att_dst1, as1, ad1, 4, HID);
  gat_agg<<<N, HC1, 0, stream>>>(hmm1, as1, ad1, offs, csr, bias1, g1o, 4, 7, 1);

  // GAT layer 2 (att dots fused into GEMM epilogue)
  gemm_k<false><<<dim3(mblocks, OUTD / 64), 256, 0, stream>>>(
      g1o, W2, nullptr, hmm2, N, OUTD, HC1, att_src2, att_dst2, as2, ad2, 1, OUTD);
  gat_agg<<<N, OUTD, 0, stream>>>(hmm2, as2, ad2, offs, csr, bias2, out, 1, 6, 0);
}